// Round 6
// baseline (418.742 us; speedup 1.0000x reference)
//
#include <hip/hip_runtime.h>

#define TTOK 2048
#define HIDN 4096
#define OPD  6144
#define DH   128
#define VD   256
#define KOFF 4096
#define VOFF 5120

typedef short  s16x8 __attribute__((ext_vector_type(8)));
typedef unsigned short u16x8 __attribute__((ext_vector_type(8)));
typedef float  fx4   __attribute__((ext_vector_type(4)));

constexpr float LAM_INIT = 0.7455692280263534f;
constexpr float OML      = 1.0f - LAM_INIT;          // (1 - lambda_init)
constexpr float QKSCALE  = 0.08838834764831845f;     // 128^-0.5
constexpr float RESCALE_THR = 8.0f;

__device__ __forceinline__ unsigned short f2bf(float f) {
  unsigned int u = __builtin_bit_cast(unsigned int, f);
  u += 0x7fffu + ((u >> 16) & 1u);   // RNE
  return (unsigned short)(u >> 16);
}

__device__ __forceinline__ void g2l16(const void* gsrc, void* ldst) {
  __builtin_amdgcn_global_load_lds(
      (const __attribute__((address_space(1))) unsigned int*)gsrc,
      (__attribute__((address_space(3))) unsigned int*)ldst, 16, 0, 0);
}

// fp32 -> bf16 bulk convert, 3 tensors, 2048 elems/block (all sizes % 2048 == 0)
__global__ __launch_bounds__(256)
void cvt3(const float* __restrict__ s0, unsigned short* __restrict__ d0, int nb0,
          const float* __restrict__ s1, unsigned short* __restrict__ d1, int nb1,
          const float* __restrict__ s2, unsigned short* __restrict__ d2)
{
  const int b = blockIdx.x;
  const float* s; unsigned short* d; int base;
  if (b < nb0)            { s = s0; d = d0; base = b << 11; }
  else if (b < nb0 + nb1) { s = s1; d = d1; base = (b - nb0) << 11; }
  else                    { s = s2; d = d2; base = (b - nb0 - nb1) << 11; }
  const int i = base + (int)threadIdx.x * 8;
  const float4 a0 = *(const float4*)(s + i);
  const float4 a1 = *(const float4*)(s + i + 4);
  u16x8 v;
  v[0]=f2bf(a0.x); v[1]=f2bf(a0.y); v[2]=f2bf(a0.z); v[3]=f2bf(a0.w);
  v[4]=f2bf(a1.x); v[5]=f2bf(a1.y); v[6]=f2bf(a1.z); v[7]=f2bf(a1.w);
  *(u16x8*)(d + i) = v;
}

// C[M,N] = A[M,K] * B[N,K]^T + bias.  A,B bf16 row-major.
// 3-buffer pipeline: counted s_waitcnt vmcnt(4) + raw s_barrier — stage loads
// for tiles t+1/t+2 stay in flight across barriers (no vmcnt(0) drain in loop).
// QKVOUT: Q region -> Cp row-major bf16; K/V regions -> ctt tiled layout:
//   per (kvp, ktile): 16384 elems = [K: cc(32)x key(32)x c8(8)] [V: kc(4)x d(256)x k8(8)]
template<bool QKVOUT, bool OUTBF16>
__global__ __launch_bounds__(256)
void gemm_bf16(const unsigned short* __restrict__ A, const unsigned short* __restrict__ B,
               const float* __restrict__ bias, void* __restrict__ Cp,
               unsigned short* __restrict__ ctt, int K, int lda, int ldb, int ldc)
{
  __shared__ __align__(16) unsigned short As[3][128 * 32];
  __shared__ __align__(16) unsigned short Bs[3][128 * 32];
  const int tid  = threadIdx.x;
  const int lane = tid & 63, wid = tid >> 6;
  const int wr = wid >> 1, wc = wid & 1;       // 2x2 wave grid, 64x64 out each
  const int m0 = blockIdx.y * 128, n0 = blockIdx.x * 128;
  const int l15 = lane & 15, lg = lane >> 4;
  const int row = tid >> 2;                    // 0..63
  const int c8  = (tid & 3) << 3;

  fx4 acc[4][4] = {};

  // stage K-tile (32 cols) at col kt into buffer buf: 4 loads/thread (2 A + 2 B)
  auto stage = [&](int kt, int buf) {
    #pragma unroll
    for (int it = 0; it < 2; ++it) {
      const int r  = it * 64 + row;
      const int s2 = it * 256 + tid;
      g2l16(A + (size_t)(m0 + r) * lda + kt + c8, &As[buf][s2 * 8]);
      g2l16(B + (size_t)(n0 + r) * ldb + kt + c8, &Bs[buf][s2 * 8]);
    }
  };

  const int nk = K >> 5;
  stage(0, 0);
  if (nk > 1) stage(32, 1);

  for (int t = 0; t < nk; ++t) {
    // Wait for OWN stage(t) loads (newest 4 = stage(t+1) stay outstanding),
    // then raw barrier: since every wave did the same wait, stage(t) is
    // fully LDS-visible block-wide. No vmcnt(0) drain inside the loop.
    if (t < nk - 1) { asm volatile("s_waitcnt vmcnt(4)\n\ts_barrier" ::: "memory"); }
    else            { asm volatile("s_waitcnt vmcnt(0)\n\ts_barrier" ::: "memory"); }
    __builtin_amdgcn_sched_barrier(0);
    // buffer (t+2)%3 was last read at iter t-1; all its reads retired pre-barrier
    if (t + 2 < nk) stage((t + 2) << 5, (t + 2) % 3);

    const unsigned short* as = As[t % 3];
    const unsigned short* bs = Bs[t % 3];
    s16x8 af[4], bf[4];
    #pragma unroll
    for (int i = 0; i < 4; ++i) {
      af[i] = *(const s16x8*)&as[(wr * 64 + i * 16 + l15) * 32 + lg * 8];
      bf[i] = *(const s16x8*)&bs[(wc * 64 + i * 16 + l15) * 32 + lg * 8];
    }
    #pragma unroll
    for (int mi = 0; mi < 4; ++mi)
      #pragma unroll
      for (int ni = 0; ni < 4; ++ni)
        acc[mi][ni] = __builtin_amdgcn_mfma_f32_16x16x32_bf16(af[mi], bf[ni], acc[mi][ni], 0, 0, 0);
  }

  const int r0 = m0 + wr * 64;
  const int c0 = n0 + wc * 64;
  if (QKVOUT && n0 >= VOFF) {
    // V region -> ctt tiled, ushort4 over 4 consecutive keys
    #pragma unroll
    for (int mi = 0; mi < 4; ++mi)
      #pragma unroll
      for (int ni = 0; ni < 4; ++ni) {
        const int col = c0 + ni * 16 + l15;
        const float bv = bias[col];
        const fx4 a = acc[mi][ni];
        ushort4 pk;
        pk.x = f2bf(a[0] + bv); pk.y = f2bf(a[1] + bv);
        pk.z = f2bf(a[2] + bv); pk.w = f2bf(a[3] + bv);
        const int d   = col - VOFF;
        const int kvp = d >> 8, dw = d & 255;
        const int row0 = r0 + mi * 16 + lg * 4;      // key
        const int kt2 = row0 >> 5, kk = row0 & 31;
        const int kc = kk >> 3, k8 = kk & 7;
        *(ushort4*)&ctt[(size_t)kvp * 1048576 + (size_t)kt2 * 16384 + 8192
                        + kc * 2048 + dw * 8 + k8] = pk;
      }
  } else if (QKVOUT && n0 >= KOFF) {
    // K region -> ctt tiled, scalar stores
    #pragma unroll
    for (int mi = 0; mi < 4; ++mi)
      #pragma unroll
      for (int ni = 0; ni < 4; ++ni) {
        const int ccol = c0 + ni * 16 + l15 - KOFF;  // 0..1023
        const float bv = bias[c0 + ni * 16 + l15];
        const int kvp = ccol >> 8, cw = ccol & 255;
        const int cc = cw >> 3, cb = cw & 7;
        const fx4 a = acc[mi][ni];
        #pragma unroll
        for (int jj = 0; jj < 4; ++jj) {
          const int row2 = r0 + mi * 16 + lg * 4 + jj;   // key
          const int kt2 = row2 >> 5, kk = row2 & 31;
          ctt[(size_t)kvp * 1048576 + (size_t)kt2 * 16384 + cc * 256 + kk * 8 + cb]
              = f2bf(a[jj] + bv);
        }
      }
  } else {
    #pragma unroll
    for (int mi = 0; mi < 4; ++mi)
      #pragma unroll
      for (int ni = 0; ni < 4; ++ni) {
        const int col = c0 + ni * 16 + l15;
        const float bv = bias[col];
        const fx4 a = acc[mi][ni];
        #pragma unroll
        for (int jj = 0; jj < 4; ++jj) {
          const int row2 = r0 + mi * 16 + lg * 4 + jj;
          const float v = a[jj] + bv;
          if (OUTBF16) ((unsigned short*)Cp)[(size_t)row2 * ldc + col] = f2bf(v);
          else         ((float*)Cp)[(size_t)row2 * ldc + col] = v;
        }
      }
  }
}

// Block = (pair, 64 q-rows), 4 waves (16 rows each, both diff components).
// K/V staged per 32-key tile via global_load_lds from the tile-contiguous ctt,
// double-buffered, ONE barrier per tile. All fragment ds_reads conflict-free.
__global__ __launch_bounds__(256, 2)
void attn_kernel(const unsigned short* __restrict__ qq,    // [TTOK][HIDN] bf16 Q
                 const unsigned short* __restrict__ ctt,   // tiled K/V
                 const float* __restrict__ lq1, const float* __restrict__ lk1,
                 const float* __restrict__ lq2, const float* __restrict__ lk2,
                 const float* __restrict__ subln,
                 unsigned short* __restrict__ attn_out)    // [TTOK][HIDN] bf16
{
  __shared__ __align__(16) unsigned short Sb[2][16384];    // [K 16KB][V 16KB]
  __shared__ __align__(16) unsigned short Pl[4][2][640];
  const int tid = threadIdx.x;
  const int lane = tid & 63, w = tid >> 6;
  const int l15 = lane & 15, lg = lane >> 4;

  // block decode: kvp -> XCD affinity, heavy q-blocks first
  const int bid = blockIdx.x;
  const int g = bid & 7, s = bid >> 3;
  const int kvp  = g >> 1;
  const int pair = kvp * 4 + (s & 3);
  const int qb   = 31 - ((s >> 2) << 1) - (g & 1);
  const int q0b  = qb * 64;
  const int q0w  = q0b + w * 16;
  const int nt   = 2 * qb + 2;

  const unsigned short* cbase = ctt + (size_t)kvp * 1048576;

  // stage tile kt (32KB linear) into Sb[buf]: 8 x global_load_lds(16B) per wave
  auto stage = [&](int kt, int buf) {
    const unsigned short* src = cbase + (size_t)kt * 16384;
    const int off = w * 512 + lane * 8;
    #pragma unroll
    for (int i = 0; i < 8; ++i) {
      const int o = i * 2048 + off;
      g2l16(src + o, &Sb[buf][o]);
    }
  };

  stage(0, 0);

  // lambda via wave-parallel dot
  float a1 = lq1[lane] * lk1[lane] + lq1[lane + 64] * lk1[lane + 64];
  float a2 = lq2[lane] * lk2[lane] + lq2[lane + 64] * lk2[lane + 64];
  #pragma unroll
  for (int sft = 1; sft < 64; sft <<= 1) { a1 += __shfl_xor(a1, sft); a2 += __shfl_xor(a2, sft); }
  const float lam = __expf(a1) - __expf(a2) + LAM_INIT;

  // Q fragments
  s16x8 qf0[4], qf1[4];
  {
    const unsigned short* qbp = qq + (size_t)(q0w + l15) * HIDN + pair * VD + lg * 8;
    #pragma unroll
    for (int kf = 0; kf < 4; ++kf) {
      qf0[kf] = *(const s16x8*)(qbp + kf * 32);
      qf1[kf] = *(const s16x8*)(qbp + DH + kf * 32);
    }
  }

  float mrun0 = -1e30f, mrun1 = -1e30f;
  float lrun0 = 0.f, lrun1 = 0.f;
  fx4 oacc0[16] = {}, oacc1[16] = {};
  unsigned short* pl0 = &Pl[w][0][0];
  unsigned short* pl1 = &Pl[w][1][0];
  const int q = q0w + l15;
  const int qmax = q0w + 15;

  for (int t = 0; t < nt; ++t) {
    __syncthreads();                      // stage(t) visible; buf[(t+1)&1] free
    if (t + 1 < nt) stage(t + 1, (t + 1) & 1);
    const int kb = t * 32;
    if (kb > qmax) continue;              // wave-uniform; still hits barrier next iter
    const unsigned short* Kl = Sb[t & 1];
    const unsigned short* Vl = Sb[t & 1] + 8192;

    // ---- QK^T swapped: S^T[key][q]
    fx4 s00 = {0,0,0,0}, s01 = {0,0,0,0}, s10 = {0,0,0,0}, s11 = {0,0,0,0};
    #pragma unroll
    for (int kf = 0; kf < 4; ++kf) {
      const int cc0 = kf * 4 + lg;        // comp0 chunks
      const int cc1 = 16 + kf * 4 + lg;   // comp1 chunks
      const s16x8 k00 = *(const s16x8*)&Kl[cc0 * 256 + l15 * 8];
      const s16x8 k01 = *(const s16x8*)&Kl[cc0 * 256 + (16 + l15) * 8];
      const s16x8 k10 = *(const s16x8*)&Kl[cc1 * 256 + l15 * 8];
      const s16x8 k11 = *(const s16x8*)&Kl[cc1 * 256 + (16 + l15) * 8];
      s00 = __builtin_amdgcn_mfma_f32_16x16x32_bf16(k00, qf0[kf], s00, 0, 0, 0);
      s01 = __builtin_amdgcn_mfma_f32_16x16x32_bf16(k01, qf0[kf], s01, 0, 0, 0);
      s10 = __builtin_amdgcn_mfma_f32_16x16x32_bf16(k10, qf1[kf], s10, 0, 0, 0);
      s11 = __builtin_amdgcn_mfma_f32_16x16x32_bf16(k11, qf1[kf], s11, 0, 0, 0);
    }

    // ---- mask + scale
    float v0[8], v1[8];
    #pragma unroll
    for (int j = 0; j < 4; ++j) {
      const int klo = kb + lg * 4 + j, khi = klo + 16;
      v0[j]     = (klo <= q) ? s00[j] * QKSCALE : -1e30f;
      v0[4 + j] = (khi <= q) ? s01[j] * QKSCALE : -1e30f;
      v1[j]     = (klo <= q) ? s10[j] * QKSCALE : -1e30f;
      v1[4 + j] = (khi <= q) ? s11[j] * QKSCALE : -1e30f;
    }
    // ---- tile max per comp
    float tm0 = fmaxf(fmaxf(fmaxf(v0[0],v0[1]),fmaxf(v0[2],v0[3])),
                      fmaxf(fmaxf(v0[4],v0[5]),fmaxf(v0[6],v0[7])));
    float tm1 = fmaxf(fmaxf(fmaxf(v1[0],v1[1]),fmaxf(v1[2],v1[3])),
                      fmaxf(fmaxf(v1[4],v1[5]),fmaxf(v1[6],v1[7])));
    tm0 = fmaxf(tm0, __shfl_xor(tm0, 16)); tm0 = fmaxf(tm0, __shfl_xor(tm0, 32));
    tm1 = fmaxf(tm1, __shfl_xor(tm1, 16)); tm1 = fmaxf(tm1, __shfl_xor(tm1, 32));

    // ---- defer-max rescale (rare)
    const bool need = (tm0 > mrun0 + RESCALE_THR) || (tm1 > mrun1 + RESCALE_THR);
    if (__any(need)) {
      const float mn0 = fmaxf(mrun0, tm0), mn1 = fmaxf(mrun1, tm1);
      const float fac0 = __expf(mrun0 - mn0), fac1 = __expf(mrun1 - mn1);
      mrun0 = mn0; mrun1 = mn1;
      lrun0 *= fac0; lrun1 *= fac1;
      #pragma unroll
      for (int jj = 0; jj < 4; ++jj) {
        const float fr0 = __shfl(fac0, lg * 4 + jj);
        const float fr1 = __shfl(fac1, lg * 4 + jj);
        #pragma unroll
        for (int nf = 0; nf < 16; ++nf) { oacc0[nf][jj] *= fr0; oacc1[nf][jj] *= fr1; }
      }
    }

    // ---- P = exp(v - mrun), pack bf16 -> per-wave LDS transpose
    {
      float ps0 = 0.f, ps1 = 0.f;
      ushort4 lo0, hi0, lo1, hi1;
      float p;
      p = __expf(v0[0]-mrun0); ps0 += p; lo0.x = f2bf(p);
      p = __expf(v0[1]-mrun0); ps0 += p; lo0.y = f2bf(p);
      p = __expf(v0[2]-mrun0); ps0 += p; lo0.z = f2bf(p);
      p = __expf(v0[3]-mrun0); ps0 += p; lo0.w = f2bf(p);
      p = __expf(v0[4]-mrun0); ps0 += p; hi0.x = f2bf(p);
      p = __expf(v0[5]-mrun0); ps0 += p; hi0.y = f2bf(p);
      p = __expf(v0[6]-mrun0); ps0 += p; hi0.z = f2bf(p);
      p = __expf(v0[7]-mrun0); ps0 += p; hi0.w = f2bf(p);
      p = __expf(v1[0]-mrun1); ps1 += p; lo1.x = f2bf(p);
      p = __expf(v1[1]-mrun1); ps1 += p; lo1.y = f2bf(p);
      p = __expf(v1[2]-mrun1); ps1 += p; lo1.z = f2bf(p);
      p = __expf(v1[3]-mrun1); ps1 += p; lo1.w = f2bf(p);
      p = __expf(v1[4]-mrun1); ps1 += p; hi1.x = f2bf(p);
      p = __expf(v1[5]-mrun1); ps1 += p; hi1.y = f2bf(p);
      p = __expf(v1[6]-mrun1); ps1 += p; hi1.z = f2bf(p);
      p = __expf(v1[7]-mrun1); ps1 += p; hi1.w = f2bf(p);
      lrun0 += ps0; lrun1 += ps1;
      *(ushort4*)&pl0[l15 * 40 + lg * 4]      = lo0;
      *(ushort4*)&pl0[l15 * 40 + 16 + lg * 4] = hi0;
      *(ushort4*)&pl1[l15 * 40 + lg * 4]      = lo1;
      *(ushort4*)&pl1[l15 * 40 + 16 + lg * 4] = hi1;
    }
    asm volatile("s_waitcnt lgkmcnt(0)" ::: "memory");
    __builtin_amdgcn_sched_barrier(0);

    // ---- PV from LDS V tile (conflict-free layout)
    const s16x8 pa0 = *(const s16x8*)&pl0[l15 * 40 + lg * 8];
    const s16x8 pa1 = *(const s16x8*)&pl1[l15 * 40 + lg * 8];
    #pragma unroll
    for (int nf = 0; nf < 16; ++nf) {
      const s16x8 vf = *(const s16x8*)&Vl[lg * 2048 + (nf * 16 + l15) * 8];
      oacc0[nf] = __builtin_amdgcn_mfma_f32_16x16x32_bf16(pa0, vf, oacc0[nf], 0, 0, 0);
      oacc1[nf] = __builtin_amdgcn_mfma_f32_16x16x32_bf16(pa1, vf, oacc1[nf], 0, 0, 0);
    }
  }

  // ---- finalize row sums
  lrun0 += __shfl_xor(lrun0, 16); lrun0 += __shfl_xor(lrun0, 32);
  lrun1 += __shfl_xor(lrun1, 16); lrun1 += __shfl_xor(lrun1, 32);

  float li0[4], li1[4];
  #pragma unroll
  for (int jj = 0; jj < 4; ++jj) {
    li0[jj] = 1.0f / __shfl(lrun0, lg * 4 + jj);
    li1[jj] = 1.0f / __shfl(lrun1, lg * 4 + jj);
  }

  // ---- combine, RMSNorm over 256, scale, store
  float ss[4] = {0.f, 0.f, 0.f, 0.f};
  #pragma unroll
  for (int nf = 0; nf < 16; ++nf)
    #pragma unroll
    for (int jj = 0; jj < 4; ++jj) {
      const float o = oacc0[nf][jj] * li0[jj] - lam * oacc1[nf][jj] * li1[jj];
      oacc0[nf][jj] = o;
      ss[jj] += o * o;
    }
  #pragma unroll
  for (int jj = 0; jj < 4; ++jj) {
    ss[jj] += __shfl_xor(ss[jj], 1);
    ss[jj] += __shfl_xor(ss[jj], 2);
    ss[jj] += __shfl_xor(ss[jj], 4);
    ss[jj] += __shfl_xor(ss[jj], 8);
    ss[jj] = rsqrtf(ss[jj] * (1.0f / 256.0f) + 1e-5f) * OML;
  }
  #pragma unroll
  for (int nf = 0; nf < 16; ++nf) {
    const int dcol = nf * 16 + l15;
    const float sw = subln[dcol];
    #pragma unroll
    for (int jj = 0; jj < 4; ++jj) {
      const int t = q0w + lg * 4 + jj;
      attn_out[(size_t)t * HIDN + pair * VD + dcol] = f2bf(oacc0[nf][jj] * ss[jj] * sw);
    }
  }
}

extern "C" void kernel_launch(void* const* d_in, const int* in_sizes, int n_in,
                              void* d_out, int out_size, void* d_ws, size_t ws_size,
                              hipStream_t stream) {
  (void)in_sizes; (void)n_in; (void)out_size; (void)ws_size;
  const float* hs     = (const float*)d_in[0];
  const float* wqkv_w = (const float*)d_in[1];
  const float* wqkv_b = (const float*)d_in[2];
  const float* lq1    = (const float*)d_in[3];
  const float* lk1    = (const float*)d_in[4];
  const float* lq2    = (const float*)d_in[5];
  const float* lk2    = (const float*)d_in[6];
  const float* subln  = (const float*)d_in[7];
  const float* out_w  = (const float*)d_in[8];
  const float* out_b  = (const float*)d_in[9];

  // ws layout (all bf16/ushort):
  //   qq [2048][4096] | ctt 4x1048576 | attn_out [2048][4096]
  //   hs_bf [2048*4096] | wqkv_bf [6144*4096] | outw_bf [4096*4096]   (~126 MB)
  unsigned short* qq       = (unsigned short*)d_ws;
  unsigned short* ctt      = qq + (size_t)TTOK * HIDN;
  unsigned short* attn_out = ctt + (size_t)4 * 1048576;
  unsigned short* hs_bf    = attn_out + (size_t)TTOK * HIDN;
  unsigned short* wqkv_bf  = hs_bf + (size_t)TTOK * HIDN;
  unsigned short* outw_bf  = wqkv_bf + (size_t)OPD * HIDN;

  const int nb0 = (TTOK * HIDN) >> 11;          // 4096
  const int nb1 = (OPD * HIDN) >> 11;           // 12288
  const int nb2 = (HIDN * HIDN) >> 11;          // 8192
  cvt3<<<dim3(nb0 + nb1 + nb2), 256, 0, stream>>>(
      hs, hs_bf, nb0, wqkv_w, wqkv_bf, nb1, out_w, outw_bf);

  // GEMM1: Q -> qq row-major; K/V -> ctt tiled
  gemm_bf16<true, true><<<dim3(OPD / 128, TTOK / 128), 256, 0, stream>>>(
      hs_bf, wqkv_bf, wqkv_b, qq, ctt, HIDN, HIDN, HIDN, HIDN);

  // Attention + combine + RMSNorm -> attn_out (bf16)
  attn_kernel<<<dim3(512), 256, 0, stream>>>(
      qq, ctt, lq1, lk1, lq2, lk2, subln, attn_out);

  // GEMM2: out = attn_out @ out_w^T + out_b  (fp32 out)
  gemm_bf16<false, false><<<dim3(HIDN / 128, TTOK / 128), 256, 0, stream>>>(
      attn_out, outw_bf, out_b, d_out, nullptr, HIDN, HIDN, HIDN, HIDN);
}

// Round 7
// 406.571 us; speedup vs baseline: 1.0299x; 1.0299x over previous
//
#include <hip/hip_runtime.h>

#define TTOK 2048
#define HIDN 4096
#define OPD  6144
#define DH   128
#define VD   256
#define KOFF 4096
#define VOFF 5120

typedef short  s16x8 __attribute__((ext_vector_type(8)));
typedef unsigned short u16x8 __attribute__((ext_vector_type(8)));
typedef float  fx4   __attribute__((ext_vector_type(4)));

constexpr float LAM_INIT = 0.7455692280263534f;
constexpr float OML      = 1.0f - LAM_INIT;          // (1 - lambda_init)
constexpr float QKSCALE  = 0.08838834764831845f;     // 128^-0.5
constexpr float RESCALE_THR = 8.0f;

__device__ __forceinline__ unsigned short f2bf(float f) {
  unsigned int u = __builtin_bit_cast(unsigned int, f);
  u += 0x7fffu + ((u >> 16) & 1u);   // RNE
  return (unsigned short)(u >> 16);
}

__device__ __forceinline__ void g2l16(const void* gsrc, void* ldst) {
  __builtin_amdgcn_global_load_lds(
      (const __attribute__((address_space(1))) unsigned int*)gsrc,
      (__attribute__((address_space(3))) unsigned int*)ldst, 16, 0, 0);
}

// fp32 -> bf16 bulk convert, 3 tensors, 2048 elems/block (all sizes % 2048 == 0)
__global__ __launch_bounds__(256)
void cvt3(const float* __restrict__ s0, unsigned short* __restrict__ d0, int nb0,
          const float* __restrict__ s1, unsigned short* __restrict__ d1, int nb1,
          const float* __restrict__ s2, unsigned short* __restrict__ d2)
{
  const int b = blockIdx.x;
  const float* s; unsigned short* d; int base;
  if (b < nb0)            { s = s0; d = d0; base = b << 11; }
  else if (b < nb0 + nb1) { s = s1; d = d1; base = (b - nb0) << 11; }
  else                    { s = s2; d = d2; base = (b - nb0 - nb1) << 11; }
  const int i = base + (int)threadIdx.x * 8;
  const float4 a0 = *(const float4*)(s + i);
  const float4 a1 = *(const float4*)(s + i + 4);
  u16x8 v;
  v[0]=f2bf(a0.x); v[1]=f2bf(a0.y); v[2]=f2bf(a0.z); v[3]=f2bf(a0.w);
  v[4]=f2bf(a1.x); v[5]=f2bf(a1.y); v[6]=f2bf(a1.z); v[7]=f2bf(a1.w);
  *(u16x8*)(d + i) = v;
}

// C[M,N] = A[M,K] * B[N,K]^T + bias, bf16 in.  512 thr / 8 waves (2M x 4N),
// wave-tile (MW*16) x 64, BK=32, 3 LDS buffers, depth-3 in-flight staging with
// counted vmcnt (never 0 mid-loop), 2 barriers + setprio'd MFMA cluster per step.
// QKVOUT: Q cols -> Cp row-major bf16; K/V cols -> ctt tiled layout:
//   per (kvp, ktile): 16384 elems = [K: cc(32)x key(32)x c8(8)] [V: kc(4)x d(256)x k8(8)]
template<int MW, bool QKVOUT, bool OUTBF16>
__global__ __launch_bounds__(512, 2)
void gemm_mfma(const unsigned short* __restrict__ A, const unsigned short* __restrict__ B,
               const float* __restrict__ bias, void* __restrict__ Cp,
               unsigned short* __restrict__ ctt, int K, int lda, int ldb, int ldc)
{
  constexpr int BM  = MW * 32;          // 2 m-waves * MW*16 rows
  constexpr int ALD = BM / 128;         // A-loads per thread per stage (2 or 1)
  __shared__ __align__(16) unsigned short As[3][BM * 32];
  __shared__ __align__(16) unsigned short Bs[3][256 * 32];

  const int tid  = threadIdx.x;
  const int lane = tid & 63, wid = tid >> 6;
  const int wm = wid >> 2, wn = wid & 3;          // 2 x 4 wave grid
  const int m0 = blockIdx.y * BM, n0 = blockIdx.x * 256;
  const int l15 = lane & 15, lg = lane >> 4;

  fx4 acc[MW][4] = {};

  // stage one BK=32 tile into buffer buf: LPS = ALD + 2 loads per thread
  auto stage = [&](int kt, int buf) {
    #pragma unroll
    for (int it = 0; it < ALD; ++it) {
      const int li = it * 512 + tid;
      g2l16(A + (size_t)(m0 + (li >> 2)) * lda + kt + ((li & 3) << 3), &As[buf][li * 8]);
    }
    #pragma unroll
    for (int it = 0; it < 2; ++it) {
      const int li = it * 512 + tid;
      g2l16(B + (size_t)(n0 + (li >> 2)) * ldb + kt + ((li & 3) << 3), &Bs[buf][li * 8]);
    }
  };

  const int nk = K >> 5;
  stage(0, 0);
  stage(32, 1);
  stage(64, 2);

  for (int t = 0; t < nk; ++t) {
    // wait for stage(t) only; stages t+1, t+2 stay in flight across the barrier
    if (t < nk - 2) {
      if (ALD == 2) asm volatile("s_waitcnt vmcnt(8)" ::: "memory");
      else          asm volatile("s_waitcnt vmcnt(6)" ::: "memory");
    } else if (t == nk - 2) {
      if (ALD == 2) asm volatile("s_waitcnt vmcnt(4)" ::: "memory");
      else          asm volatile("s_waitcnt vmcnt(3)" ::: "memory");
    } else {
      asm volatile("s_waitcnt vmcnt(0)" ::: "memory");
    }
    __builtin_amdgcn_s_barrier();
    __builtin_amdgcn_sched_barrier(0);

    const unsigned short* as = As[t % 3];
    const unsigned short* bs = Bs[t % 3];
    s16x8 af[MW], bf[4];
    #pragma unroll
    for (int mi = 0; mi < MW; ++mi)
      af[mi] = *(const s16x8*)&as[(wm * (MW * 16) + mi * 16 + l15) * 32 + lg * 8];
    #pragma unroll
    for (int ni = 0; ni < 4; ++ni)
      bf[ni] = *(const s16x8*)&bs[(wn * 64 + ni * 16 + l15) * 32 + lg * 8];
    asm volatile("s_waitcnt lgkmcnt(0)" ::: "memory");
    __builtin_amdgcn_sched_barrier(0);
    __builtin_amdgcn_s_barrier();          // all waves done reading buf t%3

    if (t + 3 < nk) stage((t + 3) << 5, (t + 3) % 3);  // overwrite buf t%3
    __builtin_amdgcn_sched_barrier(0);

    __builtin_amdgcn_s_setprio(1);
    #pragma unroll
    for (int mi = 0; mi < MW; ++mi)
      #pragma unroll
      for (int ni = 0; ni < 4; ++ni)
        acc[mi][ni] = __builtin_amdgcn_mfma_f32_16x16x32_bf16(af[mi], bf[ni], acc[mi][ni], 0, 0, 0);
    __builtin_amdgcn_s_setprio(0);
    __builtin_amdgcn_sched_barrier(0);
  }

  const int r0 = m0 + wm * (MW * 16);
  const int c0 = n0 + wn * 64;
  if (QKVOUT && n0 >= VOFF) {
    // V cols -> ctt tiled, ushort4 over 4 consecutive keys
    #pragma unroll
    for (int mi = 0; mi < MW; ++mi)
      #pragma unroll
      for (int ni = 0; ni < 4; ++ni) {
        const int col = c0 + ni * 16 + l15;
        const float bv = bias[col];
        const fx4 a = acc[mi][ni];
        ushort4 pk;
        pk.x = f2bf(a[0] + bv); pk.y = f2bf(a[1] + bv);
        pk.z = f2bf(a[2] + bv); pk.w = f2bf(a[3] + bv);
        const int d   = col - VOFF;
        const int kvp = d >> 8, dw = d & 255;
        const int row0 = r0 + mi * 16 + lg * 4;      // key
        const int kt2 = row0 >> 5, kk = row0 & 31;
        const int kc = kk >> 3, k8 = kk & 7;
        *(ushort4*)&ctt[(size_t)kvp * 1048576 + (size_t)kt2 * 16384 + 8192
                        + kc * 2048 + dw * 8 + k8] = pk;
      }
  } else if (QKVOUT && n0 >= KOFF) {
    // K cols -> ctt tiled, scalar stores
    #pragma unroll
    for (int mi = 0; mi < MW; ++mi)
      #pragma unroll
      for (int ni = 0; ni < 4; ++ni) {
        const int ccol = c0 + ni * 16 + l15 - KOFF;  // 0..1023
        const float bv = bias[c0 + ni * 16 + l15];
        const int kvp = ccol >> 8, cw = ccol & 255;
        const int cc = cw >> 3, cb = cw & 7;
        const fx4 a = acc[mi][ni];
        #pragma unroll
        for (int jj = 0; jj < 4; ++jj) {
          const int row2 = r0 + mi * 16 + lg * 4 + jj;   // key
          const int kt2 = row2 >> 5, kk = row2 & 31;
          ctt[(size_t)kvp * 1048576 + (size_t)kt2 * 16384 + cc * 256 + kk * 8 + cb]
              = f2bf(a[jj] + bv);
        }
      }
  } else {
    #pragma unroll
    for (int mi = 0; mi < MW; ++mi)
      #pragma unroll
      for (int ni = 0; ni < 4; ++ni) {
        const int col = c0 + ni * 16 + l15;
        const float bv = bias[col];
        const fx4 a = acc[mi][ni];
        #pragma unroll
        for (int jj = 0; jj < 4; ++jj) {
          const int row2 = r0 + mi * 16 + lg * 4 + jj;
          const float v = a[jj] + bv;
          if (OUTBF16) ((unsigned short*)Cp)[(size_t)row2 * ldc + col] = f2bf(v);
          else         ((float*)Cp)[(size_t)row2 * ldc + col] = v;
        }
      }
  }
}

// Block = (pair, 64 q-rows), 4 waves (16 rows each, both diff components).
// K/V staged per 32-key tile via global_load_lds from the tile-contiguous ctt,
// double-buffered, ONE barrier per tile. All fragment ds_reads conflict-free.
__global__ __launch_bounds__(256, 2)
void attn_kernel(const unsigned short* __restrict__ qq,    // [TTOK][HIDN] bf16 Q
                 const unsigned short* __restrict__ ctt,   // tiled K/V
                 const float* __restrict__ lq1, const float* __restrict__ lk1,
                 const float* __restrict__ lq2, const float* __restrict__ lk2,
                 const float* __restrict__ subln,
                 unsigned short* __restrict__ attn_out)    // [TTOK][HIDN] bf16
{
  __shared__ __align__(16) unsigned short Sb[2][16384];    // [K 16KB][V 16KB]
  __shared__ __align__(16) unsigned short Pl[4][2][640];
  const int tid = threadIdx.x;
  const int lane = tid & 63, w = tid >> 6;
  const int l15 = lane & 15, lg = lane >> 4;

  // block decode: kvp -> XCD affinity, heavy q-blocks first
  const int bid = blockIdx.x;
  const int g = bid & 7, s = bid >> 3;
  const int kvp  = g >> 1;
  const int pair = kvp * 4 + (s & 3);
  const int qb   = 31 - ((s >> 2) << 1) - (g & 1);
  const int q0b  = qb * 64;
  const int q0w  = q0b + w * 16;
  const int nt   = 2 * qb + 2;

  const unsigned short* cbase = ctt + (size_t)kvp * 1048576;

  // stage tile kt (32KB linear) into Sb[buf]: 8 x global_load_lds(16B) per wave
  auto stage = [&](int kt, int buf) {
    const unsigned short* src = cbase + (size_t)kt * 16384;
    const int off = w * 512 + lane * 8;
    #pragma unroll
    for (int i = 0; i < 8; ++i) {
      const int o = i * 2048 + off;
      g2l16(src + o, &Sb[buf][o]);
    }
  };

  stage(0, 0);

  // lambda via wave-parallel dot
  float a1 = lq1[lane] * lk1[lane] + lq1[lane + 64] * lk1[lane + 64];
  float a2 = lq2[lane] * lk2[lane] + lq2[lane + 64] * lk2[lane + 64];
  #pragma unroll
  for (int sft = 1; sft < 64; sft <<= 1) { a1 += __shfl_xor(a1, sft); a2 += __shfl_xor(a2, sft); }
  const float lam = __expf(a1) - __expf(a2) + LAM_INIT;

  // Q fragments
  s16x8 qf0[4], qf1[4];
  {
    const unsigned short* qbp = qq + (size_t)(q0w + l15) * HIDN + pair * VD + lg * 8;
    #pragma unroll
    for (int kf = 0; kf < 4; ++kf) {
      qf0[kf] = *(const s16x8*)(qbp + kf * 32);
      qf1[kf] = *(const s16x8*)(qbp + DH + kf * 32);
    }
  }

  float mrun0 = -1e30f, mrun1 = -1e30f;
  float lrun0 = 0.f, lrun1 = 0.f;
  fx4 oacc0[16] = {}, oacc1[16] = {};
  unsigned short* pl0 = &Pl[w][0][0];
  unsigned short* pl1 = &Pl[w][1][0];
  const int q = q0w + l15;
  const int qmax = q0w + 15;

  for (int t = 0; t < nt; ++t) {
    __syncthreads();                      // stage(t) visible; buf[(t+1)&1] free
    if (t + 1 < nt) stage(t + 1, (t + 1) & 1);
    const int kb = t * 32;
    if (kb > qmax) continue;              // wave-uniform; still hits barrier next iter
    const unsigned short* Kl = Sb[t & 1];
    const unsigned short* Vl = Sb[t & 1] + 8192;

    // ---- QK^T swapped: S^T[key][q]
    fx4 s00 = {0,0,0,0}, s01 = {0,0,0,0}, s10 = {0,0,0,0}, s11 = {0,0,0,0};
    #pragma unroll
    for (int kf = 0; kf < 4; ++kf) {
      const int cc0 = kf * 4 + lg;        // comp0 chunks
      const int cc1 = 16 + kf * 4 + lg;   // comp1 chunks
      const s16x8 k00 = *(const s16x8*)&Kl[cc0 * 256 + l15 * 8];
      const s16x8 k01 = *(const s16x8*)&Kl[cc0 * 256 + (16 + l15) * 8];
      const s16x8 k10 = *(const s16x8*)&Kl[cc1 * 256 + l15 * 8];
      const s16x8 k11 = *(const s16x8*)&Kl[cc1 * 256 + (16 + l15) * 8];
      s00 = __builtin_amdgcn_mfma_f32_16x16x32_bf16(k00, qf0[kf], s00, 0, 0, 0);
      s01 = __builtin_amdgcn_mfma_f32_16x16x32_bf16(k01, qf0[kf], s01, 0, 0, 0);
      s10 = __builtin_amdgcn_mfma_f32_16x16x32_bf16(k10, qf1[kf], s10, 0, 0, 0);
      s11 = __builtin_amdgcn_mfma_f32_16x16x32_bf16(k11, qf1[kf], s11, 0, 0, 0);
    }

    // ---- mask + scale
    float v0[8], v1[8];
    #pragma unroll
    for (int j = 0; j < 4; ++j) {
      const int klo = kb + lg * 4 + j, khi = klo + 16;
      v0[j]     = (klo <= q) ? s00[j] * QKSCALE : -1e30f;
      v0[4 + j] = (khi <= q) ? s01[j] * QKSCALE : -1e30f;
      v1[j]     = (klo <= q) ? s10[j] * QKSCALE : -1e30f;
      v1[4 + j] = (khi <= q) ? s11[j] * QKSCALE : -1e30f;
    }
    // ---- tile max per comp
    float tm0 = fmaxf(fmaxf(fmaxf(v0[0],v0[1]),fmaxf(v0[2],v0[3])),
                      fmaxf(fmaxf(v0[4],v0[5]),fmaxf(v0[6],v0[7])));
    float tm1 = fmaxf(fmaxf(fmaxf(v1[0],v1[1]),fmaxf(v1[2],v1[3])),
                      fmaxf(fmaxf(v1[4],v1[5]),fmaxf(v1[6],v1[7])));
    tm0 = fmaxf(tm0, __shfl_xor(tm0, 16)); tm0 = fmaxf(tm0, __shfl_xor(tm0, 32));
    tm1 = fmaxf(tm1, __shfl_xor(tm1, 16)); tm1 = fmaxf(tm1, __shfl_xor(tm1, 32));

    // ---- defer-max rescale (rare)
    const bool need = (tm0 > mrun0 + RESCALE_THR) || (tm1 > mrun1 + RESCALE_THR);
    if (__any(need)) {
      const float mn0 = fmaxf(mrun0, tm0), mn1 = fmaxf(mrun1, tm1);
      const float fac0 = __expf(mrun0 - mn0), fac1 = __expf(mrun1 - mn1);
      mrun0 = mn0; mrun1 = mn1;
      lrun0 *= fac0; lrun1 *= fac1;
      #pragma unroll
      for (int jj = 0; jj < 4; ++jj) {
        const float fr0 = __shfl(fac0, lg * 4 + jj);
        const float fr1 = __shfl(fac1, lg * 4 + jj);
        #pragma unroll
        for (int nf = 0; nf < 16; ++nf) { oacc0[nf][jj] *= fr0; oacc1[nf][jj] *= fr1; }
      }
    }

    // ---- P = exp(v - mrun), pack bf16 -> per-wave LDS transpose
    {
      float ps0 = 0.f, ps1 = 0.f;
      ushort4 lo0, hi0, lo1, hi1;
      float p;
      p = __expf(v0[0]-mrun0); ps0 += p; lo0.x = f2bf(p);
      p = __expf(v0[1]-mrun0); ps0 += p; lo0.y = f2bf(p);
      p = __expf(v0[2]-mrun0); ps0 += p; lo0.z = f2bf(p);
      p = __expf(v0[3]-mrun0); ps0 += p; lo0.w = f2bf(p);
      p = __expf(v0[4]-mrun0); ps0 += p; hi0.x = f2bf(p);
      p = __expf(v0[5]-mrun0); ps0 += p; hi0.y = f2bf(p);
      p = __expf(v0[6]-mrun0); ps0 += p; hi0.z = f2bf(p);
      p = __expf(v0[7]-mrun0); ps0 += p; hi0.w = f2bf(p);
      p = __expf(v1[0]-mrun1); ps1 += p; lo1.x = f2bf(p);
      p = __expf(v1[1]-mrun1); ps1 += p; lo1.y = f2bf(p);
      p = __expf(v1[2]-mrun1); ps1 += p; lo1.z = f2bf(p);
      p = __expf(v1[3]-mrun1); ps1 += p; lo1.w = f2bf(p);
      p = __expf(v1[4]-mrun1); ps1 += p; hi1.x = f2bf(p);
      p = __expf(v1[5]-mrun1); ps1 += p; hi1.y = f2bf(p);
      p = __expf(v1[6]-mrun1); ps1 += p; hi1.z = f2bf(p);
      p = __expf(v1[7]-mrun1); ps1 += p; hi1.w = f2bf(p);
      lrun0 += ps0; lrun1 += ps1;
      *(ushort4*)&pl0[l15 * 40 + lg * 4]      = lo0;
      *(ushort4*)&pl0[l15 * 40 + 16 + lg * 4] = hi0;
      *(ushort4*)&pl1[l15 * 40 + lg * 4]      = lo1;
      *(ushort4*)&pl1[l15 * 40 + 16 + lg * 4] = hi1;
    }
    asm volatile("s_waitcnt lgkmcnt(0)" ::: "memory");
    __builtin_amdgcn_sched_barrier(0);

    // ---- PV from LDS V tile (conflict-free layout)
    const s16x8 pa0 = *(const s16x8*)&pl0[l15 * 40 + lg * 8];
    const s16x8 pa1 = *(const s16x8*)&pl1[l15 * 40 + lg * 8];
    #pragma unroll
    for (int nf = 0; nf < 16; ++nf) {
      const s16x8 vf = *(const s16x8*)&Vl[lg * 2048 + (nf * 16 + l15) * 8];
      oacc0[nf] = __builtin_amdgcn_mfma_f32_16x16x32_bf16(pa0, vf, oacc0[nf], 0, 0, 0);
      oacc1[nf] = __builtin_amdgcn_mfma_f32_16x16x32_bf16(pa1, vf, oacc1[nf], 0, 0, 0);
    }
  }

  // ---- finalize row sums
  lrun0 += __shfl_xor(lrun0, 16); lrun0 += __shfl_xor(lrun0, 32);
  lrun1 += __shfl_xor(lrun1, 16); lrun1 += __shfl_xor(lrun1, 32);

  float li0[4], li1[4];
  #pragma unroll
  for (int jj = 0; jj < 4; ++jj) {
    li0[jj] = 1.0f / __shfl(lrun0, lg * 4 + jj);
    li1[jj] = 1.0f / __shfl(lrun1, lg * 4 + jj);
  }

  // ---- combine, RMSNorm over 256, scale, store
  float ss[4] = {0.f, 0.f, 0.f, 0.f};
  #pragma unroll
  for (int nf = 0; nf < 16; ++nf)
    #pragma unroll
    for (int jj = 0; jj < 4; ++jj) {
      const float o = oacc0[nf][jj] * li0[jj] - lam * oacc1[nf][jj] * li1[jj];
      oacc0[nf][jj] = o;
      ss[jj] += o * o;
    }
  #pragma unroll
  for (int jj = 0; jj < 4; ++jj) {
    ss[jj] += __shfl_xor(ss[jj], 1);
    ss[jj] += __shfl_xor(ss[jj], 2);
    ss[jj] += __shfl_xor(ss[jj], 4);
    ss[jj] += __shfl_xor(ss[jj], 8);
    ss[jj] = rsqrtf(ss[jj] * (1.0f / 256.0f) + 1e-5f) * OML;
  }
  #pragma unroll
  for (int nf = 0; nf < 16; ++nf) {
    const int dcol = nf * 16 + l15;
    const float sw = subln[dcol];
    #pragma unroll
    for (int jj = 0; jj < 4; ++jj) {
      const int t = q0w + lg * 4 + jj;
      attn_out[(size_t)t * HIDN + pair * VD + dcol] = f2bf(oacc0[nf][jj] * ss[jj] * sw);
    }
  }
}

extern "C" void kernel_launch(void* const* d_in, const int* in_sizes, int n_in,
                              void* d_out, int out_size, void* d_ws, size_t ws_size,
                              hipStream_t stream) {
  (void)in_sizes; (void)n_in; (void)out_size; (void)ws_size;
  const float* hs     = (const float*)d_in[0];
  const float* wqkv_w = (const float*)d_in[1];
  const float* wqkv_b = (const float*)d_in[2];
  const float* lq1    = (const float*)d_in[3];
  const float* lk1    = (const float*)d_in[4];
  const float* lq2    = (const float*)d_in[5];
  const float* lk2    = (const float*)d_in[6];
  const float* subln  = (const float*)d_in[7];
  const float* out_w  = (const float*)d_in[8];
  const float* out_b  = (const float*)d_in[9];

  // ws layout (all bf16/ushort):
  //   qq [2048][4096] | ctt 4x1048576 | attn_out [2048][4096]
  //   hs_bf [2048*4096] | wqkv_bf [6144*4096] | outw_bf [4096*4096]   (~126 MB)
  unsigned short* qq       = (unsigned short*)d_ws;
  unsigned short* ctt      = qq + (size_t)TTOK * HIDN;
  unsigned short* attn_out = ctt + (size_t)4 * 1048576;
  unsigned short* hs_bf    = attn_out + (size_t)TTOK * HIDN;
  unsigned short* wqkv_bf  = hs_bf + (size_t)TTOK * HIDN;
  unsigned short* outw_bf  = wqkv_bf + (size_t)OPD * HIDN;

  const int nb0 = (TTOK * HIDN) >> 11;          // 4096
  const int nb1 = (OPD * HIDN) >> 11;           // 12288
  const int nb2 = (HIDN * HIDN) >> 11;          // 8192
  cvt3<<<dim3(nb0 + nb1 + nb2), 256, 0, stream>>>(
      hs, hs_bf, nb0, wqkv_w, wqkv_bf, nb1, out_w, outw_bf);

  // GEMM1: 256x256 tile; Q -> qq row-major; K/V -> ctt tiled (region-aligned blocks)
  gemm_mfma<8, true, true><<<dim3(OPD / 256, TTOK / 256), 512, 0, stream>>>(
      hs_bf, wqkv_bf, wqkv_b, qq, ctt, HIDN, HIDN, HIDN, HIDN);

  // Attention + combine + RMSNorm -> attn_out (bf16)
  attn_kernel<<<dim3(512), 256, 0, stream>>>(
      qq, ctt, lq1, lk1, lq2, lk2, subln, attn_out);

  // GEMM2: 128x256 tile; out = attn_out @ out_w^T + out_b  (fp32 out)
  gemm_mfma<4, false, false><<<dim3(HIDN / 256, TTOK / 128), 512, 0, stream>>>(
      attn_out, outw_bf, out_b, d_out, nullptr, HIDN, HIDN, HIDN, HIDN);
}

// Round 8
// 375.977 us; speedup vs baseline: 1.1137x; 1.0814x over previous
//
#include <hip/hip_runtime.h>

#define TTOK 2048
#define HIDN 4096
#define OPD  6144
#define DH   128
#define VD   256
#define KOFF 4096
#define VOFF 5120

typedef short  s16x8 __attribute__((ext_vector_type(8)));
typedef unsigned short u16x8 __attribute__((ext_vector_type(8)));
typedef float  fx4   __attribute__((ext_vector_type(4)));

constexpr float LAM_INIT = 0.7455692280263534f;
constexpr float OML      = 1.0f - LAM_INIT;          // (1 - lambda_init)
constexpr float QKSCALE  = 0.08838834764831845f;     // 128^-0.5
constexpr float RESCALE_THR = 8.0f;

__device__ __forceinline__ unsigned short f2bf(float f) {
  unsigned int u = __builtin_bit_cast(unsigned int, f);
  u += 0x7fffu + ((u >> 16) & 1u);   // RNE
  return (unsigned short)(u >> 16);
}

__device__ __forceinline__ void g2l16(const void* gsrc, void* ldst) {
  __builtin_amdgcn_global_load_lds(
      (const __attribute__((address_space(1))) unsigned int*)gsrc,
      (__attribute__((address_space(3))) unsigned int*)ldst, 16, 0, 0);
}

// fp32 -> bf16 bulk convert, 3 tensors, 2048 elems/block (all sizes % 2048 == 0)
__global__ __launch_bounds__(256)
void cvt3(const float* __restrict__ s0, unsigned short* __restrict__ d0, int nb0,
          const float* __restrict__ s1, unsigned short* __restrict__ d1, int nb1,
          const float* __restrict__ s2, unsigned short* __restrict__ d2)
{
  const int b = blockIdx.x;
  const float* s; unsigned short* d; int base;
  if (b < nb0)            { s = s0; d = d0; base = b << 11; }
  else if (b < nb0 + nb1) { s = s1; d = d1; base = (b - nb0) << 11; }
  else                    { s = s2; d = d2; base = (b - nb0 - nb1) << 11; }
  const int i = base + (int)threadIdx.x * 8;
  const float4 a0 = *(const float4*)(s + i);
  const float4 a1 = *(const float4*)(s + i + 4);
  u16x8 v;
  v[0]=f2bf(a0.x); v[1]=f2bf(a0.y); v[2]=f2bf(a0.z); v[3]=f2bf(a0.w);
  v[4]=f2bf(a1.x); v[5]=f2bf(a1.y); v[6]=f2bf(a1.z); v[7]=f2bf(a1.w);
  *(u16x8*)(d + i) = v;
}

// C[M,N] = A[M,K] * B[N,K]^T + bias, bf16 in.  8-phase-style schedule:
// 512 thr / 8 waves (2M x 4N), wave-tile (MW*16) x 64, BK=64, 2 K-tile LDS dbuf,
// 4 sub-phases per K-tile {ds_read subtile | stage part | barrier | lgkm |
// setprio MFMA quadrant | barrier}, stage front-loaded, single vmcnt(0)/tile.
// LDS XOR-swizzle: elem_col ^= ((row&7)<<3), applied on the global_load_lds
// SOURCE and the ds_read column (involution; row&7==l15&7 -> folds to consts).
// QKVOUT: Q cols -> Cp row-major bf16; K/V cols -> ctt tiled layout:
//   per (kvp, ktile): 16384 elems = [K: cc(32)x key(32)x c8(8)] [V: kc(4)x d(256)x k8(8)]
template<int MW, bool QKVOUT, bool OUTBF16>
__global__ __launch_bounds__(512, 2)
void gemm_8ph(const unsigned short* __restrict__ A, const unsigned short* __restrict__ B,
              const float* __restrict__ bias, void* __restrict__ Cp,
              unsigned short* __restrict__ ctt, int K, int lda, int ldb, int ldc)
{
  constexpr int BM  = MW * 32;            // 256 (MW=8) or 128 (MW=4)
  constexpr int ALD = BM / 64;            // A gload_lds per thread per K-tile
  __shared__ __align__(16) unsigned short As[2][BM * 64];
  __shared__ __align__(16) unsigned short Bs[2][256 * 64];

  const int tid  = threadIdx.x;
  const int lane = tid & 63, wid = tid >> 6;
  const int wm = wid >> 2, wn = wid & 3;            // 2 x 4 wave grid
  const int m0 = blockIdx.y * BM, n0 = blockIdx.x * 256;
  const int l15 = lane & 15, lg = lane >> 4;

  // staging: linear LDS dest, inverse-swizzled global source
  const int srow = tid >> 3;                                  // 0..63
  const int scol = ((tid & 7) ^ ((tid >> 3) & 7)) << 3;       // swizzled col (elems)
  // fragment reads: swizzled column constants (row&7 == l15&7 for all frags)
  const int rsw = (l15 & 7) << 3;
  const int ck0 = (lg * 8) ^ rsw;                             // kk=0 chunk
  const int ck1 = (32 + lg * 8) ^ rsw;                        // kk=1 chunk
  const int arow = wm * (MW * 16) + l15;
  const int brow = wn * 64 + l15;

  auto stageA = [&](int kt, int buf) {
    #pragma unroll
    for (int it = 0; it < ALD; ++it)
      g2l16(A + (size_t)(m0 + it * 64 + srow) * lda + kt + scol,
            &As[buf][(it * 512 + tid) * 8]);
  };
  auto stageB = [&](int kt, int buf, int h) {
    #pragma unroll
    for (int it = h * 2; it < h * 2 + 2; ++it)
      g2l16(B + (size_t)(n0 + it * 64 + srow) * ldb + kt + scol,
            &Bs[buf][(it * 512 + tid) * 8]);
  };

  fx4 acc[MW][4] = {};

  const int nk = K >> 6;
  stageA(0, 0); stageB(0, 0, 0); stageB(0, 0, 1);
  asm volatile("s_waitcnt vmcnt(0)" ::: "memory");
  __builtin_amdgcn_s_barrier();

  for (int t = 0; t < nk; ++t) {
    const unsigned short* as = As[t & 1];
    const unsigned short* bs = Bs[t & 1];
    const int kt1 = (t + 1) << 6;
    const int nb  = (t + 1) & 1;
    const bool pre = (t + 1) < nk;
    s16x8 af[MW], bf[4];

    // ---------- phase 0: kk0 | ni 0-1 ----------
    #pragma unroll
    for (int mi = 0; mi < MW; ++mi)
      af[mi] = *(const s16x8*)&as[(arow + mi * 16) * 64 + ck0];
    bf[0] = *(const s16x8*)&bs[(brow +  0) * 64 + ck0];
    bf[1] = *(const s16x8*)&bs[(brow + 16) * 64 + ck0];
    if (pre) { stageA(kt1, nb); stageB(kt1, nb, 0); }
    __builtin_amdgcn_s_barrier();
    asm volatile("s_waitcnt lgkmcnt(0)" ::: "memory");
    __builtin_amdgcn_sched_barrier(0);
    __builtin_amdgcn_s_setprio(1);
    #pragma unroll
    for (int mi = 0; mi < MW; ++mi) {
      acc[mi][0] = __builtin_amdgcn_mfma_f32_16x16x32_bf16(af[mi], bf[0], acc[mi][0], 0, 0, 0);
      acc[mi][1] = __builtin_amdgcn_mfma_f32_16x16x32_bf16(af[mi], bf[1], acc[mi][1], 0, 0, 0);
    }
    __builtin_amdgcn_s_setprio(0);
    __builtin_amdgcn_s_barrier();

    // ---------- phase 1: kk0 | ni 2-3 ----------
    bf[2] = *(const s16x8*)&bs[(brow + 32) * 64 + ck0];
    bf[3] = *(const s16x8*)&bs[(brow + 48) * 64 + ck0];
    if (pre) stageB(kt1, nb, 1);
    __builtin_amdgcn_s_barrier();
    asm volatile("s_waitcnt lgkmcnt(0)" ::: "memory");
    __builtin_amdgcn_sched_barrier(0);
    __builtin_amdgcn_s_setprio(1);
    #pragma unroll
    for (int mi = 0; mi < MW; ++mi) {
      acc[mi][2] = __builtin_amdgcn_mfma_f32_16x16x32_bf16(af[mi], bf[2], acc[mi][2], 0, 0, 0);
      acc[mi][3] = __builtin_amdgcn_mfma_f32_16x16x32_bf16(af[mi], bf[3], acc[mi][3], 0, 0, 0);
    }
    __builtin_amdgcn_s_setprio(0);
    __builtin_amdgcn_s_barrier();

    // ---------- phase 2: kk1 | ni 0-1 ----------
    #pragma unroll
    for (int mi = 0; mi < MW; ++mi)
      af[mi] = *(const s16x8*)&as[(arow + mi * 16) * 64 + ck1];
    bf[0] = *(const s16x8*)&bs[(brow +  0) * 64 + ck1];
    bf[1] = *(const s16x8*)&bs[(brow + 16) * 64 + ck1];
    __builtin_amdgcn_s_barrier();
    asm volatile("s_waitcnt lgkmcnt(0)" ::: "memory");
    __builtin_amdgcn_sched_barrier(0);
    __builtin_amdgcn_s_setprio(1);
    #pragma unroll
    for (int mi = 0; mi < MW; ++mi) {
      acc[mi][0] = __builtin_amdgcn_mfma_f32_16x16x32_bf16(af[mi], bf[0], acc[mi][0], 0, 0, 0);
      acc[mi][1] = __builtin_amdgcn_mfma_f32_16x16x32_bf16(af[mi], bf[1], acc[mi][1], 0, 0, 0);
    }
    __builtin_amdgcn_s_setprio(0);
    __builtin_amdgcn_s_barrier();

    // ---------- phase 3: kk1 | ni 2-3 ----------
    bf[2] = *(const s16x8*)&bs[(brow + 32) * 64 + ck1];
    bf[3] = *(const s16x8*)&bs[(brow + 48) * 64 + ck1];
    __builtin_amdgcn_s_barrier();
    asm volatile("s_waitcnt lgkmcnt(0)" ::: "memory");
    __builtin_amdgcn_sched_barrier(0);
    __builtin_amdgcn_s_setprio(1);
    #pragma unroll
    for (int mi = 0; mi < MW; ++mi) {
      acc[mi][2] = __builtin_amdgcn_mfma_f32_16x16x32_bf16(af[mi], bf[2], acc[mi][2], 0, 0, 0);
      acc[mi][3] = __builtin_amdgcn_mfma_f32_16x16x32_bf16(af[mi], bf[3], acc[mi][3], 0, 0, 0);
    }
    __builtin_amdgcn_s_setprio(0);
    if (pre) asm volatile("s_waitcnt vmcnt(0)" ::: "memory");  // next tile landed
    __builtin_amdgcn_s_barrier();
  }

  const int r0 = m0 + wm * (MW * 16);
  const int c0 = n0 + wn * 64;
  if (QKVOUT && n0 >= VOFF) {
    // V cols -> ctt tiled, ushort4 over 4 consecutive keys
    #pragma unroll
    for (int mi = 0; mi < MW; ++mi)
      #pragma unroll
      for (int ni = 0; ni < 4; ++ni) {
        const int col = c0 + ni * 16 + l15;
        const float bv = bias[col];
        const fx4 a = acc[mi][ni];
        ushort4 pk;
        pk.x = f2bf(a[0] + bv); pk.y = f2bf(a[1] + bv);
        pk.z = f2bf(a[2] + bv); pk.w = f2bf(a[3] + bv);
        const int d   = col - VOFF;
        const int kvp = d >> 8, dw = d & 255;
        const int row0 = r0 + mi * 16 + lg * 4;      // key
        const int kt2 = row0 >> 5, kk = row0 & 31;
        const int kc = kk >> 3, k8 = kk & 7;
        *(ushort4*)&ctt[(size_t)kvp * 1048576 + (size_t)kt2 * 16384 + 8192
                        + kc * 2048 + dw * 8 + k8] = pk;
      }
  } else if (QKVOUT && n0 >= KOFF) {
    // K cols -> ctt tiled, scalar stores
    #pragma unroll
    for (int mi = 0; mi < MW; ++mi)
      #pragma unroll
      for (int ni = 0; ni < 4; ++ni) {
        const int ccol = c0 + ni * 16 + l15 - KOFF;  // 0..1023
        const float bv = bias[c0 + ni * 16 + l15];
        const int kvp = ccol >> 8, cw = ccol & 255;
        const int cc = cw >> 3, cb = cw & 7;
        const fx4 a = acc[mi][ni];
        #pragma unroll
        for (int jj = 0; jj < 4; ++jj) {
          const int row2 = r0 + mi * 16 + lg * 4 + jj;   // key
          const int kt2 = row2 >> 5, kk = row2 & 31;
          ctt[(size_t)kvp * 1048576 + (size_t)kt2 * 16384 + cc * 256 + kk * 8 + cb]
              = f2bf(a[jj] + bv);
        }
      }
  } else {
    #pragma unroll
    for (int mi = 0; mi < MW; ++mi)
      #pragma unroll
      for (int ni = 0; ni < 4; ++ni) {
        const int col = c0 + ni * 16 + l15;
        const float bv = bias[col];
        const fx4 a = acc[mi][ni];
        #pragma unroll
        for (int jj = 0; jj < 4; ++jj) {
          const int row2 = r0 + mi * 16 + lg * 4 + jj;
          const float v = a[jj] + bv;
          if (OUTBF16) ((unsigned short*)Cp)[(size_t)row2 * ldc + col] = f2bf(v);
          else         ((float*)Cp)[(size_t)row2 * ldc + col] = v;
        }
      }
  }
}

// Block = (pair, 64 q-rows), 4 waves (16 rows each, both diff components).
// K/V staged per 32-key tile via global_load_lds from the tile-contiguous ctt,
// double-buffered, ONE barrier per tile. All fragment ds_reads conflict-free.
__global__ __launch_bounds__(256, 2)
void attn_kernel(const unsigned short* __restrict__ qq,    // [TTOK][HIDN] bf16 Q
                 const unsigned short* __restrict__ ctt,   // tiled K/V
                 const float* __restrict__ lq1, const float* __restrict__ lk1,
                 const float* __restrict__ lq2, const float* __restrict__ lk2,
                 const float* __restrict__ subln,
                 unsigned short* __restrict__ attn_out)    // [TTOK][HIDN] bf16
{
  __shared__ __align__(16) unsigned short Sb[2][16384];    // [K 16KB][V 16KB]
  __shared__ __align__(16) unsigned short Pl[4][2][640];
  const int tid = threadIdx.x;
  const int lane = tid & 63, w = tid >> 6;
  const int l15 = lane & 15, lg = lane >> 4;

  // block decode: kvp -> XCD affinity, heavy q-blocks first
  const int bid = blockIdx.x;
  const int g = bid & 7, s = bid >> 3;
  const int kvp  = g >> 1;
  const int pair = kvp * 4 + (s & 3);
  const int qb   = 31 - ((s >> 2) << 1) - (g & 1);
  const int q0b  = qb * 64;
  const int q0w  = q0b + w * 16;
  const int nt   = 2 * qb + 2;

  const unsigned short* cbase = ctt + (size_t)kvp * 1048576;

  // stage tile kt (32KB linear) into Sb[buf]: 8 x global_load_lds(16B) per wave
  auto stage = [&](int kt, int buf) {
    const unsigned short* src = cbase + (size_t)kt * 16384;
    const int off = w * 512 + lane * 8;
    #pragma unroll
    for (int i = 0; i < 8; ++i) {
      const int o = i * 2048 + off;
      g2l16(src + o, &Sb[buf][o]);
    }
  };

  stage(0, 0);

  // lambda via wave-parallel dot
  float a1 = lq1[lane] * lk1[lane] + lq1[lane + 64] * lk1[lane + 64];
  float a2 = lq2[lane] * lk2[lane] + lq2[lane + 64] * lk2[lane + 64];
  #pragma unroll
  for (int sft = 1; sft < 64; sft <<= 1) { a1 += __shfl_xor(a1, sft); a2 += __shfl_xor(a2, sft); }
  const float lam = __expf(a1) - __expf(a2) + LAM_INIT;

  // Q fragments
  s16x8 qf0[4], qf1[4];
  {
    const unsigned short* qbp = qq + (size_t)(q0w + l15) * HIDN + pair * VD + lg * 8;
    #pragma unroll
    for (int kf = 0; kf < 4; ++kf) {
      qf0[kf] = *(const s16x8*)(qbp + kf * 32);
      qf1[kf] = *(const s16x8*)(qbp + DH + kf * 32);
    }
  }

  float mrun0 = -1e30f, mrun1 = -1e30f;
  float lrun0 = 0.f, lrun1 = 0.f;
  fx4 oacc0[16] = {}, oacc1[16] = {};
  unsigned short* pl0 = &Pl[w][0][0];
  unsigned short* pl1 = &Pl[w][1][0];
  const int q = q0w + l15;
  const int qmax = q0w + 15;

  for (int t = 0; t < nt; ++t) {
    __syncthreads();                      // stage(t) visible; buf[(t+1)&1] free
    if (t + 1 < nt) stage(t + 1, (t + 1) & 1);
    const int kb = t * 32;
    if (kb > qmax) continue;              // wave-uniform; still hits barrier next iter
    const unsigned short* Kl = Sb[t & 1];
    const unsigned short* Vl = Sb[t & 1] + 8192;

    // ---- QK^T swapped: S^T[key][q]
    fx4 s00 = {0,0,0,0}, s01 = {0,0,0,0}, s10 = {0,0,0,0}, s11 = {0,0,0,0};
    #pragma unroll
    for (int kf = 0; kf < 4; ++kf) {
      const int cc0 = kf * 4 + lg;        // comp0 chunks
      const int cc1 = 16 + kf * 4 + lg;   // comp1 chunks
      const s16x8 k00 = *(const s16x8*)&Kl[cc0 * 256 + l15 * 8];
      const s16x8 k01 = *(const s16x8*)&Kl[cc0 * 256 + (16 + l15) * 8];
      const s16x8 k10 = *(const s16x8*)&Kl[cc1 * 256 + l15 * 8];
      const s16x8 k11 = *(const s16x8*)&Kl[cc1 * 256 + (16 + l15) * 8];
      s00 = __builtin_amdgcn_mfma_f32_16x16x32_bf16(k00, qf0[kf], s00, 0, 0, 0);
      s01 = __builtin_amdgcn_mfma_f32_16x16x32_bf16(k01, qf0[kf], s01, 0, 0, 0);
      s10 = __builtin_amdgcn_mfma_f32_16x16x32_bf16(k10, qf1[kf], s10, 0, 0, 0);
      s11 = __builtin_amdgcn_mfma_f32_16x16x32_bf16(k11, qf1[kf], s11, 0, 0, 0);
    }

    // ---- mask + scale
    float v0[8], v1[8];
    #pragma unroll
    for (int j = 0; j < 4; ++j) {
      const int klo = kb + lg * 4 + j, khi = klo + 16;
      v0[j]     = (klo <= q) ? s00[j] * QKSCALE : -1e30f;
      v0[4 + j] = (khi <= q) ? s01[j] * QKSCALE : -1e30f;
      v1[j]     = (klo <= q) ? s10[j] * QKSCALE : -1e30f;
      v1[4 + j] = (khi <= q) ? s11[j] * QKSCALE : -1e30f;
    }
    // ---- tile max per comp
    float tm0 = fmaxf(fmaxf(fmaxf(v0[0],v0[1]),fmaxf(v0[2],v0[3])),
                      fmaxf(fmaxf(v0[4],v0[5]),fmaxf(v0[6],v0[7])));
    float tm1 = fmaxf(fmaxf(fmaxf(v1[0],v1[1]),fmaxf(v1[2],v1[3])),
                      fmaxf(fmaxf(v1[4],v1[5]),fmaxf(v1[6],v1[7])));
    tm0 = fmaxf(tm0, __shfl_xor(tm0, 16)); tm0 = fmaxf(tm0, __shfl_xor(tm0, 32));
    tm1 = fmaxf(tm1, __shfl_xor(tm1, 16)); tm1 = fmaxf(tm1, __shfl_xor(tm1, 32));

    // ---- defer-max rescale (rare)
    const bool need = (tm0 > mrun0 + RESCALE_THR) || (tm1 > mrun1 + RESCALE_THR);
    if (__any(need)) {
      const float mn0 = fmaxf(mrun0, tm0), mn1 = fmaxf(mrun1, tm1);
      const float fac0 = __expf(mrun0 - mn0), fac1 = __expf(mrun1 - mn1);
      mrun0 = mn0; mrun1 = mn1;
      lrun0 *= fac0; lrun1 *= fac1;
      #pragma unroll
      for (int jj = 0; jj < 4; ++jj) {
        const float fr0 = __shfl(fac0, lg * 4 + jj);
        const float fr1 = __shfl(fac1, lg * 4 + jj);
        #pragma unroll
        for (int nf = 0; nf < 16; ++nf) { oacc0[nf][jj] *= fr0; oacc1[nf][jj] *= fr1; }
      }
    }

    // ---- P = exp(v - mrun), pack bf16 -> per-wave LDS transpose
    {
      float ps0 = 0.f, ps1 = 0.f;
      ushort4 lo0, hi0, lo1, hi1;
      float p;
      p = __expf(v0[0]-mrun0); ps0 += p; lo0.x = f2bf(p);
      p = __expf(v0[1]-mrun0); ps0 += p; lo0.y = f2bf(p);
      p = __expf(v0[2]-mrun0); ps0 += p; lo0.z = f2bf(p);
      p = __expf(v0[3]-mrun0); ps0 += p; lo0.w = f2bf(p);
      p = __expf(v0[4]-mrun0); ps0 += p; hi0.x = f2bf(p);
      p = __expf(v0[5]-mrun0); ps0 += p; hi0.y = f2bf(p);
      p = __expf(v0[6]-mrun0); ps0 += p; hi0.z = f2bf(p);
      p = __expf(v0[7]-mrun0); ps0 += p; hi0.w = f2bf(p);
      p = __expf(v1[0]-mrun1); ps1 += p; lo1.x = f2bf(p);
      p = __expf(v1[1]-mrun1); ps1 += p; lo1.y = f2bf(p);
      p = __expf(v1[2]-mrun1); ps1 += p; lo1.z = f2bf(p);
      p = __expf(v1[3]-mrun1); ps1 += p; lo1.w = f2bf(p);
      p = __expf(v1[4]-mrun1); ps1 += p; hi1.x = f2bf(p);
      p = __expf(v1[5]-mrun1); ps1 += p; hi1.y = f2bf(p);
      p = __expf(v1[6]-mrun1); ps1 += p; hi1.z = f2bf(p);
      p = __expf(v1[7]-mrun1); ps1 += p; hi1.w = f2bf(p);
      lrun0 += ps0; lrun1 += ps1;
      *(ushort4*)&pl0[l15 * 40 + lg * 4]      = lo0;
      *(ushort4*)&pl0[l15 * 40 + 16 + lg * 4] = hi0;
      *(ushort4*)&pl1[l15 * 40 + lg * 4]      = lo1;
      *(ushort4*)&pl1[l15 * 40 + 16 + lg * 4] = hi1;
    }
    asm volatile("s_waitcnt lgkmcnt(0)" ::: "memory");
    __builtin_amdgcn_sched_barrier(0);

    // ---- PV from LDS V tile (conflict-free layout)
    const s16x8 pa0 = *(const s16x8*)&pl0[l15 * 40 + lg * 8];
    const s16x8 pa1 = *(const s16x8*)&pl1[l15 * 40 + lg * 8];
    #pragma unroll
    for (int nf = 0; nf < 16; ++nf) {
      const s16x8 vf = *(const s16x8*)&Vl[lg * 2048 + (nf * 16 + l15) * 8];
      oacc0[nf] = __builtin_amdgcn_mfma_f32_16x16x32_bf16(pa0, vf, oacc0[nf], 0, 0, 0);
      oacc1[nf] = __builtin_amdgcn_mfma_f32_16x16x32_bf16(pa1, vf, oacc1[nf], 0, 0, 0);
    }
  }

  // ---- finalize row sums
  lrun0 += __shfl_xor(lrun0, 16); lrun0 += __shfl_xor(lrun0, 32);
  lrun1 += __shfl_xor(lrun1, 16); lrun1 += __shfl_xor(lrun1, 32);

  float li0[4], li1[4];
  #pragma unroll
  for (int jj = 0; jj < 4; ++jj) {
    li0[jj] = 1.0f / __shfl(lrun0, lg * 4 + jj);
    li1[jj] = 1.0f / __shfl(lrun1, lg * 4 + jj);
  }

  // ---- combine, RMSNorm over 256, scale, store
  float ss[4] = {0.f, 0.f, 0.f, 0.f};
  #pragma unroll
  for (int nf = 0; nf < 16; ++nf)
    #pragma unroll
    for (int jj = 0; jj < 4; ++jj) {
      const float o = oacc0[nf][jj] * li0[jj] - lam * oacc1[nf][jj] * li1[jj];
      oacc0[nf][jj] = o;
      ss[jj] += o * o;
    }
  #pragma unroll
  for (int jj = 0; jj < 4; ++jj) {
    ss[jj] += __shfl_xor(ss[jj], 1);
    ss[jj] += __shfl_xor(ss[jj], 2);
    ss[jj] += __shfl_xor(ss[jj], 4);
    ss[jj] += __shfl_xor(ss[jj], 8);
    ss[jj] = rsqrtf(ss[jj] * (1.0f / 256.0f) + 1e-5f) * OML;
  }
  #pragma unroll
  for (int nf = 0; nf < 16; ++nf) {
    const int dcol = nf * 16 + l15;
    const float sw = subln[dcol];
    #pragma unroll
    for (int jj = 0; jj < 4; ++jj) {
      const int t = q0w + lg * 4 + jj;
      attn_out[(size_t)t * HIDN + pair * VD + dcol] = f2bf(oacc0[nf][jj] * ss[jj] * sw);
    }
  }
}

extern "C" void kernel_launch(void* const* d_in, const int* in_sizes, int n_in,
                              void* d_out, int out_size, void* d_ws, size_t ws_size,
                              hipStream_t stream) {
  (void)in_sizes; (void)n_in; (void)out_size; (void)ws_size;
  const float* hs     = (const float*)d_in[0];
  const float* wqkv_w = (const float*)d_in[1];
  const float* wqkv_b = (const float*)d_in[2];
  const float* lq1    = (const float*)d_in[3];
  const float* lk1    = (const float*)d_in[4];
  const float* lq2    = (const float*)d_in[5];
  const float* lk2    = (const float*)d_in[6];
  const float* subln  = (const float*)d_in[7];
  const float* out_w  = (const float*)d_in[8];
  const float* out_b  = (const float*)d_in[9];

  // ws layout (all bf16/ushort):
  //   qq [2048][4096] | ctt 4x1048576 | attn_out [2048][4096]
  //   hs_bf [2048*4096] | wqkv_bf [6144*4096] | outw_bf [4096*4096]   (~126 MB)
  unsigned short* qq       = (unsigned short*)d_ws;
  unsigned short* ctt      = qq + (size_t)TTOK * HIDN;
  unsigned short* attn_out = ctt + (size_t)4 * 1048576;
  unsigned short* hs_bf    = attn_out + (size_t)TTOK * HIDN;
  unsigned short* wqkv_bf  = hs_bf + (size_t)TTOK * HIDN;
  unsigned short* outw_bf  = wqkv_bf + (size_t)OPD * HIDN;

  const int nb0 = (TTOK * HIDN) >> 11;          // 4096
  const int nb1 = (OPD * HIDN) >> 11;           // 12288
  const int nb2 = (HIDN * HIDN) >> 11;          // 8192
  cvt3<<<dim3(nb0 + nb1 + nb2), 256, 0, stream>>>(
      hs, hs_bf, nb0, wqkv_w, wqkv_bf, nb1, out_w, outw_bf);

  // GEMM1: 256x256 tile; Q -> qq row-major; K/V -> ctt tiled (region-aligned blocks)
  gemm_8ph<8, true, true><<<dim3(OPD / 256, TTOK / 256), 512, 0, stream>>>(
      hs_bf, wqkv_bf, wqkv_b, qq, ctt, HIDN, HIDN, HIDN, HIDN);

  // Attention + combine + RMSNorm -> attn_out (bf16)
  attn_kernel<<<dim3(512), 256, 0, stream>>>(
      qq, ctt, lq1, lk1, lq2, lk2, subln, attn_out);

  // GEMM2: 128x256 tile; out = attn_out @ out_w^T + out_b  (fp32 out)
  gemm_8ph<4, false, false><<<dim3(HIDN / 256, TTOK / 128), 512, 0, stream>>>(
      attn_out, outw_bf, out_b, d_out, nullptr, HIDN, HIDN, HIDN, HIDN);
}

// Round 9
// 367.831 us; speedup vs baseline: 1.1384x; 1.0221x over previous
//
#include <hip/hip_runtime.h>

#define TTOK 2048
#define HIDN 4096
#define OPD  6144
#define DH   128
#define VD   256
#define KOFF 4096
#define VOFF 5120

typedef short  s16x8 __attribute__((ext_vector_type(8)));
typedef unsigned short u16x8 __attribute__((ext_vector_type(8)));
typedef float  fx4   __attribute__((ext_vector_type(4)));

constexpr float LAM_INIT = 0.7455692280263534f;
constexpr float OML      = 1.0f - LAM_INIT;          // (1 - lambda_init)
constexpr float QKSCALE  = 0.08838834764831845f;     // 128^-0.5
constexpr float RESCALE_THR = 8.0f;

__device__ __forceinline__ unsigned short f2bf(float f) {
  unsigned int u = __builtin_bit_cast(unsigned int, f);
  u += 0x7fffu + ((u >> 16) & 1u);   // RNE
  return (unsigned short)(u >> 16);
}

__device__ __forceinline__ void g2l16(const void* gsrc, void* ldst) {
  __builtin_amdgcn_global_load_lds(
      (const __attribute__((address_space(1))) unsigned int*)gsrc,
      (__attribute__((address_space(3))) unsigned int*)ldst, 16, 0, 0);
}

// fp32 -> bf16 bulk convert, 3 tensors, 2048 elems/block (all sizes % 2048 == 0)
__global__ __launch_bounds__(256)
void cvt3(const float* __restrict__ s0, unsigned short* __restrict__ d0, int nb0,
          const float* __restrict__ s1, unsigned short* __restrict__ d1, int nb1,
          const float* __restrict__ s2, unsigned short* __restrict__ d2)
{
  const int b = blockIdx.x;
  const float* s; unsigned short* d; int base;
  if (b < nb0)            { s = s0; d = d0; base = b << 11; }
  else if (b < nb0 + nb1) { s = s1; d = d1; base = (b - nb0) << 11; }
  else                    { s = s2; d = d2; base = (b - nb0 - nb1) << 11; }
  const int i = base + (int)threadIdx.x * 8;
  const float4 a0 = *(const float4*)(s + i);
  const float4 a1 = *(const float4*)(s + i + 4);
  u16x8 v;
  v[0]=f2bf(a0.x); v[1]=f2bf(a0.y); v[2]=f2bf(a0.z); v[3]=f2bf(a0.w);
  v[4]=f2bf(a1.x); v[5]=f2bf(a1.y); v[6]=f2bf(a1.z); v[7]=f2bf(a1.w);
  *(u16x8*)(d + i) = v;
}

// C[M,N] = A[M,K] * B[N,K]^T + bias, bf16 in.  8 waves (2M x 4N) INTERLEAVED:
// wave wm owns rows mi*32+wm*16, wave wn cols ni*64+wn*16.  BK=64, 2 K-tile
// LDS dbuf split in row-halves; 4 phases/K-tile, phase q=(mi-grp,ni-grp)
// consumes only (Ah_g, Bh_ng).  Next tile staged one half per phase
// (Ah0@q0, Bh0@q1, Bh1@q2, Ah1@q3) -> steady counted vmcnt (never 0 in loop),
// each awaited half is 3-4 phases old.  LDS XOR-swizzle (pre-swizzled global
// source + swizzled ds_read col) keeps all reads conflict-free.
// QKVOUT: Q cols -> Cp row-major bf16; K/V cols -> ctt tiled layout.
template<int MW, bool QKVOUT, bool OUTBF16>
__global__ __launch_bounds__(512, 2)
void gemm_8ph(const unsigned short* __restrict__ A, const unsigned short* __restrict__ B,
              const float* __restrict__ bias, void* __restrict__ Cp,
              unsigned short* __restrict__ ctt, int K, int lda, int ldb, int ldc)
{
  constexpr int BM   = MW * 32;          // 256 (MW=8) / 128 (MW=4)
  constexpr int MH   = MW / 2;           // mi per half-group
  constexpr int ALD2 = MW / 4;           // A gloads per half per thread
  __shared__ __align__(16) unsigned short As[2][2][(BM / 2) * 64];
  __shared__ __align__(16) unsigned short Bs[2][2][128 * 64];

  const int tid  = threadIdx.x;
  const int lane = tid & 63, wid = tid >> 6;
  const int wm = wid >> 2, wn = wid & 3;            // 2 x 4 wave grid
  const int m0 = blockIdx.y * BM, n0 = blockIdx.x * 256;
  const int l15 = lane & 15, lg = lane >> 4;

  // staging: linear LDS dest, inverse-swizzled global source
  const int srow = tid >> 3;                                  // 0..63
  const int scol = ((tid & 7) ^ ((tid >> 3) & 7)) << 3;
  // fragment reads: swizzled col constants (row&7 == l15&7 for all frags)
  const int rsw = (l15 & 7) << 3;
  const int ck0 = (lg * 8) ^ rsw;
  const int ck1 = (32 + lg * 8) ^ rsw;
  const int arh = wm * 16 + l15;        // + mi_local*32 within half
  const int brh = wn * 16 + l15;        // + ni_local*64 within half

  auto stageAh = [&](int kt, int buf, int h) {
    #pragma unroll
    for (int i = 0; i < ALD2; ++i)
      g2l16(A + (size_t)(m0 + h * (BM / 2) + i * 64 + srow) * lda + kt + scol,
            &As[buf][h][(i * 512 + tid) * 8]);
  };
  auto stageBh = [&](int kt, int buf, int h) {
    #pragma unroll
    for (int i = 0; i < 2; ++i)
      g2l16(B + (size_t)(n0 + h * 128 + i * 64 + srow) * ldb + kt + scol,
            &Bs[buf][h][(i * 512 + tid) * 8]);
  };

  fx4 acc[MW][4] = {};

  const int nk = K >> 6;
  stageAh(0, 0, 0); stageBh(0, 0, 0); stageBh(0, 0, 1); stageAh(0, 0, 1);
  asm volatile("s_waitcnt vmcnt(0)" ::: "memory");
  __builtin_amdgcn_s_barrier();

  for (int t = 0; t < nk; ++t) {
    const int buf = t & 1, nb = buf ^ 1;
    const int kt1 = (t + 1) << 6;
    const bool pre = (t + 1) < nk;
    const unsigned short* A0 = &As[buf][0][0];
    const unsigned short* A1 = &As[buf][1][0];
    const unsigned short* B0 = &Bs[buf][0][0];
    const unsigned short* B1 = &Bs[buf][1][0];
    s16x8 af[MH][2], bf[2][2];

    // ---------- q0: mi-grp 0, ni-grp 0 ----------
    #pragma unroll
    for (int m = 0; m < MH; ++m) {
      af[m][0] = *(const s16x8*)&A0[(arh + m * 32) * 64 + ck0];
      af[m][1] = *(const s16x8*)&A0[(arh + m * 32) * 64 + ck1];
    }
    #pragma unroll
    for (int n = 0; n < 2; ++n) {
      bf[n][0] = *(const s16x8*)&B0[(brh + n * 64) * 64 + ck0];
      bf[n][1] = *(const s16x8*)&B0[(brh + n * 64) * 64 + ck1];
    }
    if (pre) {
      stageAh(kt1, nb, 0);
      if constexpr (MW == 8) asm volatile("s_waitcnt vmcnt(4)" ::: "memory");
      else                   asm volatile("s_waitcnt vmcnt(2)" ::: "memory");
    } else {
      asm volatile("s_waitcnt vmcnt(0)" ::: "memory");
    }
    __builtin_amdgcn_s_barrier();
    asm volatile("s_waitcnt lgkmcnt(0)" ::: "memory");
    __builtin_amdgcn_sched_barrier(0);
    __builtin_amdgcn_s_setprio(1);
    #pragma unroll
    for (int m = 0; m < MH; ++m)
      #pragma unroll
      for (int n = 0; n < 2; ++n) {
        acc[m][n] = __builtin_amdgcn_mfma_f32_16x16x32_bf16(af[m][0], bf[n][0], acc[m][n], 0, 0, 0);
        acc[m][n] = __builtin_amdgcn_mfma_f32_16x16x32_bf16(af[m][1], bf[n][1], acc[m][n], 0, 0, 0);
      }
    __builtin_amdgcn_s_setprio(0);
    __builtin_amdgcn_s_barrier();

    // ---------- q1: mi-grp 0, ni-grp 1 ----------
    #pragma unroll
    for (int n = 0; n < 2; ++n) {
      bf[n][0] = *(const s16x8*)&B1[(brh + n * 64) * 64 + ck0];
      bf[n][1] = *(const s16x8*)&B1[(brh + n * 64) * 64 + ck1];
    }
    if (pre) {
      stageBh(kt1, nb, 0);
      if constexpr (MW == 8) asm volatile("s_waitcnt vmcnt(4)" ::: "memory");
      else                   asm volatile("s_waitcnt vmcnt(3)" ::: "memory");
    }
    __builtin_amdgcn_s_barrier();
    asm volatile("s_waitcnt lgkmcnt(0)" ::: "memory");
    __builtin_amdgcn_sched_barrier(0);
    __builtin_amdgcn_s_setprio(1);
    #pragma unroll
    for (int m = 0; m < MH; ++m)
      #pragma unroll
      for (int n = 0; n < 2; ++n) {
        acc[m][2 + n] = __builtin_amdgcn_mfma_f32_16x16x32_bf16(af[m][0], bf[n][0], acc[m][2 + n], 0, 0, 0);
        acc[m][2 + n] = __builtin_amdgcn_mfma_f32_16x16x32_bf16(af[m][1], bf[n][1], acc[m][2 + n], 0, 0, 0);
      }
    __builtin_amdgcn_s_setprio(0);
    __builtin_amdgcn_s_barrier();

    // ---------- q2: mi-grp 1, ni-grp 0 ----------
    #pragma unroll
    for (int m = 0; m < MH; ++m) {
      af[m][0] = *(const s16x8*)&A1[(arh + m * 32) * 64 + ck0];
      af[m][1] = *(const s16x8*)&A1[(arh + m * 32) * 64 + ck1];
    }
    #pragma unroll
    for (int n = 0; n < 2; ++n) {
      bf[n][0] = *(const s16x8*)&B0[(brh + n * 64) * 64 + ck0];
      bf[n][1] = *(const s16x8*)&B0[(brh + n * 64) * 64 + ck1];
    }
    if (pre) stageBh(kt1, nb, 1);       // no wait: q3 inputs gated at q0/q1
    __builtin_amdgcn_s_barrier();
    asm volatile("s_waitcnt lgkmcnt(0)" ::: "memory");
    __builtin_amdgcn_sched_barrier(0);
    __builtin_amdgcn_s_setprio(1);
    #pragma unroll
    for (int m = 0; m < MH; ++m)
      #pragma unroll
      for (int n = 0; n < 2; ++n) {
        acc[MH + m][n] = __builtin_amdgcn_mfma_f32_16x16x32_bf16(af[m][0], bf[n][0], acc[MH + m][n], 0, 0, 0);
        acc[MH + m][n] = __builtin_amdgcn_mfma_f32_16x16x32_bf16(af[m][1], bf[n][1], acc[MH + m][n], 0, 0, 0);
      }
    __builtin_amdgcn_s_setprio(0);
    __builtin_amdgcn_s_barrier();

    // ---------- q3: mi-grp 1, ni-grp 1 ----------
    #pragma unroll
    for (int n = 0; n < 2; ++n) {
      bf[n][0] = *(const s16x8*)&B1[(brh + n * 64) * 64 + ck0];
      bf[n][1] = *(const s16x8*)&B1[(brh + n * 64) * 64 + ck1];
    }
    if (pre) {
      stageAh(kt1, nb, 1);
      if constexpr (MW == 8) asm volatile("s_waitcnt vmcnt(4)" ::: "memory");
      else                   asm volatile("s_waitcnt vmcnt(3)" ::: "memory");
    }
    __builtin_amdgcn_s_barrier();
    asm volatile("s_waitcnt lgkmcnt(0)" ::: "memory");
    __builtin_amdgcn_sched_barrier(0);
    __builtin_amdgcn_s_setprio(1);
    #pragma unroll
    for (int m = 0; m < MH; ++m)
      #pragma unroll
      for (int n = 0; n < 2; ++n) {
        acc[MH + m][2 + n] = __builtin_amdgcn_mfma_f32_16x16x32_bf16(af[m][0], bf[n][0], acc[MH + m][2 + n], 0, 0, 0);
        acc[MH + m][2 + n] = __builtin_amdgcn_mfma_f32_16x16x32_bf16(af[m][1], bf[n][1], acc[MH + m][2 + n], 0, 0, 0);
      }
    __builtin_amdgcn_s_setprio(0);
    __builtin_amdgcn_s_barrier();
  }

  // epilogue: row = m0 + mi*32 + wm*16 + lg*4+jj ; col = n0 + ni*64 + wn*16 + l15
  const int rb = m0 + wm * 16;
  const int cb = n0 + wn * 16;
  if (QKVOUT && n0 >= VOFF) {
    #pragma unroll
    for (int mi = 0; mi < MW; ++mi)
      #pragma unroll
      for (int ni = 0; ni < 4; ++ni) {
        const int col = cb + ni * 64 + l15;
        const float bv = bias[col];
        const fx4 a = acc[mi][ni];
        ushort4 pk;
        pk.x = f2bf(a[0] + bv); pk.y = f2bf(a[1] + bv);
        pk.z = f2bf(a[2] + bv); pk.w = f2bf(a[3] + bv);
        const int d   = col - VOFF;
        const int kvp = d >> 8, dw = d & 255;
        const int row0 = rb + mi * 32 + lg * 4;      // key
        const int kt2 = row0 >> 5, kk = row0 & 31;
        const int kc = kk >> 3, k8 = kk & 7;
        *(ushort4*)&ctt[(size_t)kvp * 1048576 + (size_t)kt2 * 16384 + 8192
                        + kc * 2048 + dw * 8 + k8] = pk;
      }
  } else if (QKVOUT && n0 >= KOFF) {
    #pragma unroll
    for (int mi = 0; mi < MW; ++mi)
      #pragma unroll
      for (int ni = 0; ni < 4; ++ni) {
        const int col = cb + ni * 64 + l15;
        const int ccol = col - KOFF;
        const float bv = bias[col];
        const int kvp = ccol >> 8, cw = ccol & 255;
        const int cc = cw >> 3, cbt = cw & 7;
        const fx4 a = acc[mi][ni];
        #pragma unroll
        for (int jj = 0; jj < 4; ++jj) {
          const int row2 = rb + mi * 32 + lg * 4 + jj;   // key
          const int kt2 = row2 >> 5, kk = row2 & 31;
          ctt[(size_t)kvp * 1048576 + (size_t)kt2 * 16384 + cc * 256 + kk * 8 + cbt]
              = f2bf(a[jj] + bv);
        }
      }
  } else {
    #pragma unroll
    for (int mi = 0; mi < MW; ++mi)
      #pragma unroll
      for (int ni = 0; ni < 4; ++ni) {
        const int col = cb + ni * 64 + l15;
        const float bv = bias[col];
        const fx4 a = acc[mi][ni];
        #pragma unroll
        for (int jj = 0; jj < 4; ++jj) {
          const int row2 = rb + mi * 32 + lg * 4 + jj;
          const float v = a[jj] + bv;
          if (OUTBF16) ((unsigned short*)Cp)[(size_t)row2 * ldc + col] = f2bf(v);
          else         ((float*)Cp)[(size_t)row2 * ldc + col] = v;
        }
      }
  }
}

// Block = (pair, 64 q-rows), 4 waves (16 rows each, both diff components).
// K/V staged per 32-key tile via global_load_lds from the tile-contiguous ctt,
// double-buffered, ONE barrier per tile. All fragment ds_reads conflict-free.
__global__ __launch_bounds__(256, 2)
void attn_kernel(const unsigned short* __restrict__ qq,    // [TTOK][HIDN] bf16 Q
                 const unsigned short* __restrict__ ctt,   // tiled K/V
                 const float* __restrict__ lq1, const float* __restrict__ lk1,
                 const float* __restrict__ lq2, const float* __restrict__ lk2,
                 const float* __restrict__ subln,
                 unsigned short* __restrict__ attn_out)    // [TTOK][HIDN] bf16
{
  __shared__ __align__(16) unsigned short Sb[2][16384];    // [K 16KB][V 16KB]
  __shared__ __align__(16) unsigned short Pl[4][2][640];
  const int tid = threadIdx.x;
  const int lane = tid & 63, w = tid >> 6;
  const int l15 = lane & 15, lg = lane >> 4;

  // block decode: kvp -> XCD affinity, heavy q-blocks first
  const int bid = blockIdx.x;
  const int g = bid & 7, s = bid >> 3;
  const int kvp  = g >> 1;
  const int pair = kvp * 4 + (s & 3);
  const int qb   = 31 - ((s >> 2) << 1) - (g & 1);
  const int q0b  = qb * 64;
  const int q0w  = q0b + w * 16;
  const int nt   = 2 * qb + 2;

  const unsigned short* cbase = ctt + (size_t)kvp * 1048576;

  // stage tile kt (32KB linear) into Sb[buf]: 8 x global_load_lds(16B) per wave
  auto stage = [&](int kt, int buf) {
    const unsigned short* src = cbase + (size_t)kt * 16384;
    const int off = w * 512 + lane * 8;
    #pragma unroll
    for (int i = 0; i < 8; ++i) {
      const int o = i * 2048 + off;
      g2l16(src + o, &Sb[buf][o]);
    }
  };

  stage(0, 0);

  // lambda via wave-parallel dot
  float a1 = lq1[lane] * lk1[lane] + lq1[lane + 64] * lk1[lane + 64];
  float a2 = lq2[lane] * lk2[lane] + lq2[lane + 64] * lk2[lane + 64];
  #pragma unroll
  for (int sft = 1; sft < 64; sft <<= 1) { a1 += __shfl_xor(a1, sft); a2 += __shfl_xor(a2, sft); }
  const float lam = __expf(a1) - __expf(a2) + LAM_INIT;

  // Q fragments
  s16x8 qf0[4], qf1[4];
  {
    const unsigned short* qbp = qq + (size_t)(q0w + l15) * HIDN + pair * VD + lg * 8;
    #pragma unroll
    for (int kf = 0; kf < 4; ++kf) {
      qf0[kf] = *(const s16x8*)(qbp + kf * 32);
      qf1[kf] = *(const s16x8*)(qbp + DH + kf * 32);
    }
  }

  float mrun0 = -1e30f, mrun1 = -1e30f;
  float lrun0 = 0.f, lrun1 = 0.f;
  fx4 oacc0[16] = {}, oacc1[16] = {};
  unsigned short* pl0 = &Pl[w][0][0];
  unsigned short* pl1 = &Pl[w][1][0];
  const int q = q0w + l15;
  const int qmax = q0w + 15;

  for (int t = 0; t < nt; ++t) {
    __syncthreads();                      // stage(t) visible; buf[(t+1)&1] free
    if (t + 1 < nt) stage(t + 1, (t + 1) & 1);
    const int kb = t * 32;
    if (kb > qmax) continue;              // wave-uniform; still hits barrier next iter
    const unsigned short* Kl = Sb[t & 1];
    const unsigned short* Vl = Sb[t & 1] + 8192;

    // ---- QK^T swapped: S^T[key][q]
    fx4 s00 = {0,0,0,0}, s01 = {0,0,0,0}, s10 = {0,0,0,0}, s11 = {0,0,0,0};
    #pragma unroll
    for (int kf = 0; kf < 4; ++kf) {
      const int cc0 = kf * 4 + lg;        // comp0 chunks
      const int cc1 = 16 + kf * 4 + lg;   // comp1 chunks
      const s16x8 k00 = *(const s16x8*)&Kl[cc0 * 256 + l15 * 8];
      const s16x8 k01 = *(const s16x8*)&Kl[cc0 * 256 + (16 + l15) * 8];
      const s16x8 k10 = *(const s16x8*)&Kl[cc1 * 256 + l15 * 8];
      const s16x8 k11 = *(const s16x8*)&Kl[cc1 * 256 + (16 + l15) * 8];
      s00 = __builtin_amdgcn_mfma_f32_16x16x32_bf16(k00, qf0[kf], s00, 0, 0, 0);
      s01 = __builtin_amdgcn_mfma_f32_16x16x32_bf16(k01, qf0[kf], s01, 0, 0, 0);
      s10 = __builtin_amdgcn_mfma_f32_16x16x32_bf16(k10, qf1[kf], s10, 0, 0, 0);
      s11 = __builtin_amdgcn_mfma_f32_16x16x32_bf16(k11, qf1[kf], s11, 0, 0, 0);
    }

    // ---- mask + scale
    float v0[8], v1[8];
    #pragma unroll
    for (int j = 0; j < 4; ++j) {
      const int klo = kb + lg * 4 + j, khi = klo + 16;
      v0[j]     = (klo <= q) ? s00[j] * QKSCALE : -1e30f;
      v0[4 + j] = (khi <= q) ? s01[j] * QKSCALE : -1e30f;
      v1[j]     = (klo <= q) ? s10[j] * QKSCALE : -1e30f;
      v1[4 + j] = (khi <= q) ? s11[j] * QKSCALE : -1e30f;
    }
    // ---- tile max per comp
    float tm0 = fmaxf(fmaxf(fmaxf(v0[0],v0[1]),fmaxf(v0[2],v0[3])),
                      fmaxf(fmaxf(v0[4],v0[5]),fmaxf(v0[6],v0[7])));
    float tm1 = fmaxf(fmaxf(fmaxf(v1[0],v1[1]),fmaxf(v1[2],v1[3])),
                      fmaxf(fmaxf(v1[4],v1[5]),fmaxf(v1[6],v1[7])));
    tm0 = fmaxf(tm0, __shfl_xor(tm0, 16)); tm0 = fmaxf(tm0, __shfl_xor(tm0, 32));
    tm1 = fmaxf(tm1, __shfl_xor(tm1, 16)); tm1 = fmaxf(tm1, __shfl_xor(tm1, 32));

    // ---- defer-max rescale (rare)
    const bool need = (tm0 > mrun0 + RESCALE_THR) || (tm1 > mrun1 + RESCALE_THR);
    if (__any(need)) {
      const float mn0 = fmaxf(mrun0, tm0), mn1 = fmaxf(mrun1, tm1);
      const float fac0 = __expf(mrun0 - mn0), fac1 = __expf(mrun1 - mn1);
      mrun0 = mn0; mrun1 = mn1;
      lrun0 *= fac0; lrun1 *= fac1;
      #pragma unroll
      for (int jj = 0; jj < 4; ++jj) {
        const float fr0 = __shfl(fac0, lg * 4 + jj);
        const float fr1 = __shfl(fac1, lg * 4 + jj);
        #pragma unroll
        for (int nf = 0; nf < 16; ++nf) { oacc0[nf][jj] *= fr0; oacc1[nf][jj] *= fr1; }
      }
    }

    // ---- P = exp(v - mrun), pack bf16 -> per-wave LDS transpose
    {
      float ps0 = 0.f, ps1 = 0.f;
      ushort4 lo0, hi0, lo1, hi1;
      float p;
      p = __expf(v0[0]-mrun0); ps0 += p; lo0.x = f2bf(p);
      p = __expf(v0[1]-mrun0); ps0 += p; lo0.y = f2bf(p);
      p = __expf(v0[2]-mrun0); ps0 += p; lo0.z = f2bf(p);
      p = __expf(v0[3]-mrun0); ps0 += p; lo0.w = f2bf(p);
      p = __expf(v0[4]-mrun0); ps0 += p; hi0.x = f2bf(p);
      p = __expf(v0[5]-mrun0); ps0 += p; hi0.y = f2bf(p);
      p = __expf(v0[6]-mrun0); ps0 += p; hi0.z = f2bf(p);
      p = __expf(v0[7]-mrun0); ps0 += p; hi0.w = f2bf(p);
      p = __expf(v1[0]-mrun1); ps1 += p; lo1.x = f2bf(p);
      p = __expf(v1[1]-mrun1); ps1 += p; lo1.y = f2bf(p);
      p = __expf(v1[2]-mrun1); ps1 += p; lo1.z = f2bf(p);
      p = __expf(v1[3]-mrun1); ps1 += p; lo1.w = f2bf(p);
      p = __expf(v1[4]-mrun1); ps1 += p; hi1.x = f2bf(p);
      p = __expf(v1[5]-mrun1); ps1 += p; hi1.y = f2bf(p);
      p = __expf(v1[6]-mrun1); ps1 += p; hi1.z = f2bf(p);
      p = __expf(v1[7]-mrun1); ps1 += p; hi1.w = f2bf(p);
      lrun0 += ps0; lrun1 += ps1;
      *(ushort4*)&pl0[l15 * 40 + lg * 4]      = lo0;
      *(ushort4*)&pl0[l15 * 40 + 16 + lg * 4] = hi0;
      *(ushort4*)&pl1[l15 * 40 + lg * 4]      = lo1;
      *(ushort4*)&pl1[l15 * 40 + 16 + lg * 4] = hi1;
    }
    asm volatile("s_waitcnt lgkmcnt(0)" ::: "memory");
    __builtin_amdgcn_sched_barrier(0);

    // ---- PV from LDS V tile (conflict-free layout)
    const s16x8 pa0 = *(const s16x8*)&pl0[l15 * 40 + lg * 8];
    const s16x8 pa1 = *(const s16x8*)&pl1[l15 * 40 + lg * 8];
    #pragma unroll
    for (int nf = 0; nf < 16; ++nf) {
      const s16x8 vf = *(const s16x8*)&Vl[lg * 2048 + (nf * 16 + l15) * 8];
      oacc0[nf] = __builtin_amdgcn_mfma_f32_16x16x32_bf16(pa0, vf, oacc0[nf], 0, 0, 0);
      oacc1[nf] = __builtin_amdgcn_mfma_f32_16x16x32_bf16(pa1, vf, oacc1[nf], 0, 0, 0);
    }
  }

  // ---- finalize row sums
  lrun0 += __shfl_xor(lrun0, 16); lrun0 += __shfl_xor(lrun0, 32);
  lrun1 += __shfl_xor(lrun1, 16); lrun1 += __shfl_xor(lrun1, 32);

  float li0[4], li1[4];
  #pragma unroll
  for (int jj = 0; jj < 4; ++jj) {
    li0[jj] = 1.0f / __shfl(lrun0, lg * 4 + jj);
    li1[jj] = 1.0f / __shfl(lrun1, lg * 4 + jj);
  }

  // ---- combine, RMSNorm over 256, scale, store
  float ss[4] = {0.f, 0.f, 0.f, 0.f};
  #pragma unroll
  for (int nf = 0; nf < 16; ++nf)
    #pragma unroll
    for (int jj = 0; jj < 4; ++jj) {
      const float o = oacc0[nf][jj] * li0[jj] - lam * oacc1[nf][jj] * li1[jj];
      oacc0[nf][jj] = o;
      ss[jj] += o * o;
    }
  #pragma unroll
  for (int jj = 0; jj < 4; ++jj) {
    ss[jj] += __shfl_xor(ss[jj], 1);
    ss[jj] += __shfl_xor(ss[jj], 2);
    ss[jj] += __shfl_xor(ss[jj], 4);
    ss[jj] += __shfl_xor(ss[jj], 8);
    ss[jj] = rsqrtf(ss[jj] * (1.0f / 256.0f) + 1e-5f) * OML;
  }
  #pragma unroll
  for (int nf = 0; nf < 16; ++nf) {
    const int dcol = nf * 16 + l15;
    const float sw = subln[dcol];
    #pragma unroll
    for (int jj = 0; jj < 4; ++jj) {
      const int t = q0w + lg * 4 + jj;
      attn_out[(size_t)t * HIDN + pair * VD + dcol] = f2bf(oacc0[nf][jj] * ss[jj] * sw);
    }
  }
}

extern "C" void kernel_launch(void* const* d_in, const int* in_sizes, int n_in,
                              void* d_out, int out_size, void* d_ws, size_t ws_size,
                              hipStream_t stream) {
  (void)in_sizes; (void)n_in; (void)out_size; (void)ws_size;
  const float* hs     = (const float*)d_in[0];
  const float* wqkv_w = (const float*)d_in[1];
  const float* wqkv_b = (const float*)d_in[2];
  const float* lq1    = (const float*)d_in[3];
  const float* lk1    = (const float*)d_in[4];
  const float* lq2    = (const float*)d_in[5];
  const float* lk2    = (const float*)d_in[6];
  const float* subln  = (const float*)d_in[7];
  const float* out_w  = (const float*)d_in[8];
  const float* out_b  = (const float*)d_in[9];

  // ws layout (all bf16/ushort):
  //   qq [2048][4096] | ctt 4x1048576 | attn_out [2048][4096]
  //   hs_bf [2048*4096] | wqkv_bf [6144*4096] | outw_bf [4096*4096]   (~126 MB)
  unsigned short* qq       = (unsigned short*)d_ws;
  unsigned short* ctt      = qq + (size_t)TTOK * HIDN;
  unsigned short* attn_out = ctt + (size_t)4 * 1048576;
  unsigned short* hs_bf    = attn_out + (size_t)TTOK * HIDN;
  unsigned short* wqkv_bf  = hs_bf + (size_t)TTOK * HIDN;
  unsigned short* outw_bf  = wqkv_bf + (size_t)OPD * HIDN;

  const int nb0 = (TTOK * HIDN) >> 11;          // 4096
  const int nb1 = (OPD * HIDN) >> 11;           // 12288
  const int nb2 = (HIDN * HIDN) >> 11;          // 8192
  cvt3<<<dim3(nb0 + nb1 + nb2), 256, 0, stream>>>(
      hs, hs_bf, nb0, wqkv_w, wqkv_bf, nb1, out_w, outw_bf);

  // GEMM1: 256x256 tile; Q -> qq row-major; K/V -> ctt tiled (region-aligned blocks)
  gemm_8ph<8, true, true><<<dim3(OPD / 256, TTOK / 256), 512, 0, stream>>>(
      hs_bf, wqkv_bf, wqkv_b, qq, ctt, HIDN, HIDN, HIDN, HIDN);

  // Attention + combine + RMSNorm -> attn_out (bf16)
  attn_kernel<<<dim3(512), 256, 0, stream>>>(
      qq, ctt, lq1, lk1, lq2, lk2, subln, attn_out);

  // GEMM2: 128x256 tile; out = attn_out @ out_w^T + out_b  (fp32 out)
  gemm_8ph<4, false, false><<<dim3(HIDN / 256, TTOK / 128), 512, 0, stream>>>(
      attn_out, outw_bf, out_b, d_out, nullptr, HIDN, HIDN, HIDN, HIDN);
}

// Round 10
// 357.084 us; speedup vs baseline: 1.1727x; 1.0301x over previous
//
#include <hip/hip_runtime.h>

#define TTOK 2048
#define HIDN 4096
#define OPD  6144
#define DH   128
#define VD   256
#define KOFF 4096
#define VOFF 5120

typedef short  s16x8 __attribute__((ext_vector_type(8)));
typedef unsigned short u16x8 __attribute__((ext_vector_type(8)));
typedef float  fx4   __attribute__((ext_vector_type(4)));

constexpr float LAM_INIT = 0.7455692280263534f;
constexpr float OML      = 1.0f - LAM_INIT;          // (1 - lambda_init)
constexpr float QKSCALE  = 0.08838834764831845f;     // 128^-0.5
constexpr float RESCALE_THR = 8.0f;

__device__ __forceinline__ unsigned short f2bf(float f) {
  unsigned int u = __builtin_bit_cast(unsigned int, f);
  u += 0x7fffu + ((u >> 16) & 1u);   // RNE
  return (unsigned short)(u >> 16);
}

__device__ __forceinline__ void g2l16(const void* gsrc, void* ldst) {
  __builtin_amdgcn_global_load_lds(
      (const __attribute__((address_space(1))) unsigned int*)gsrc,
      (__attribute__((address_space(3))) unsigned int*)ldst, 16, 0, 0);
}

// fp32 -> bf16 bulk convert, 3 tensors, 2048 elems/block (all sizes % 2048 == 0)
__global__ __launch_bounds__(256)
void cvt3(const float* __restrict__ s0, unsigned short* __restrict__ d0, int nb0,
          const float* __restrict__ s1, unsigned short* __restrict__ d1, int nb1,
          const float* __restrict__ s2, unsigned short* __restrict__ d2)
{
  const int b = blockIdx.x;
  const float* s; unsigned short* d; int base;
  if (b < nb0)            { s = s0; d = d0; base = b << 11; }
  else if (b < nb0 + nb1) { s = s1; d = d1; base = (b - nb0) << 11; }
  else                    { s = s2; d = d2; base = (b - nb0 - nb1) << 11; }
  const int i = base + (int)threadIdx.x * 8;
  const float4 a0 = *(const float4*)(s + i);
  const float4 a1 = *(const float4*)(s + i + 4);
  u16x8 v;
  v[0]=f2bf(a0.x); v[1]=f2bf(a0.y); v[2]=f2bf(a0.z); v[3]=f2bf(a0.w);
  v[4]=f2bf(a1.x); v[5]=f2bf(a1.y); v[6]=f2bf(a1.z); v[7]=f2bf(a1.w);
  *(u16x8*)(d + i) = v;
}

// C[M,N] = A[M,K] * B[N,K]^T + bias, bf16 in.  8 waves (2M x 4N) interleaved.
// BK=64, 2 K-tile LDS dbuf in row-halves.  4 phases/K-tile, order
// (A0B0)(A0B1)(A1B1)(A1B0) so each phase swaps ONE operand register set.
// Stage next tile one half per phase; waits q0/q1/q3 (counted, never 0 in
// steady state); barriers ONLY after waits (3/K-tile).  No manual lgkmcnt --
// ds_reads are IR loads, compiler inserts fine-grained waits and interleaves
// next-phase reads into MFMA clusters.  LDS XOR-swizzle keeps reads
// conflict-free (pre-swizzled global source + swizzled ds_read col).
// QKVOUT: Q cols -> Cp row-major bf16; K/V cols -> ctt tiled layout.
template<int MW, bool QKVOUT, bool OUTBF16>
__global__ __launch_bounds__(512, 2)
void gemm_8ph(const unsigned short* __restrict__ A, const unsigned short* __restrict__ B,
              const float* __restrict__ bias, void* __restrict__ Cp,
              unsigned short* __restrict__ ctt, int K, int lda, int ldb, int ldc)
{
  constexpr int BM   = MW * 32;          // 256 (MW=8) / 128 (MW=4)
  constexpr int MH   = MW / 2;           // mi per half-group
  constexpr int ALD2 = MW / 4;           // A gloads per half per thread
  __shared__ __align__(16) unsigned short As[2][2][(BM / 2) * 64];
  __shared__ __align__(16) unsigned short Bs[2][2][128 * 64];

  const int tid  = threadIdx.x;
  const int lane = tid & 63, wid = tid >> 6;
  const int wm = wid >> 2, wn = wid & 3;            // 2 x 4 wave grid
  const int m0 = blockIdx.y * BM, n0 = blockIdx.x * 256;
  const int l15 = lane & 15, lg = lane >> 4;

  // staging: linear LDS dest, inverse-swizzled global source
  const int srow = tid >> 3;                                  // 0..63
  const int scol = ((tid & 7) ^ ((tid >> 3) & 7)) << 3;
  // fragment reads: swizzled col constants (row&7 == l15&7 for all frags)
  const int rsw = (l15 & 7) << 3;
  const int ck0 = (lg * 8) ^ rsw;
  const int ck1 = (32 + lg * 8) ^ rsw;
  const int arh = wm * 16 + l15;        // + mi_local*32 within half
  const int brh = wn * 16 + l15;        // + ni_local*64 within half

  auto stageAh = [&](int kt, int buf, int h) {
    #pragma unroll
    for (int i = 0; i < ALD2; ++i)
      g2l16(A + (size_t)(m0 + h * (BM / 2) + i * 64 + srow) * lda + kt + scol,
            &As[buf][h][(i * 512 + tid) * 8]);
  };
  auto stageBh = [&](int kt, int buf, int h) {
    #pragma unroll
    for (int i = 0; i < 2; ++i)
      g2l16(B + (size_t)(n0 + h * 128 + i * 64 + srow) * ldb + kt + scol,
            &Bs[buf][h][(i * 512 + tid) * 8]);
  };

  fx4 acc[MW][4] = {};

  const int nk = K >> 6;
  stageAh(0, 0, 0); stageBh(0, 0, 0); stageBh(0, 0, 1); stageAh(0, 0, 1);
  asm volatile("s_waitcnt vmcnt(0)" ::: "memory");
  __builtin_amdgcn_s_barrier();

  for (int t = 0; t < nk; ++t) {
    const int buf = t & 1, nb = buf ^ 1;
    const int kt1 = (t + 1) << 6;
    const bool pre = (t + 1) < nk;
    const unsigned short* A0 = &As[buf][0][0];
    const unsigned short* A1 = &As[buf][1][0];
    const unsigned short* B0 = &Bs[buf][0][0];
    const unsigned short* B1 = &Bs[buf][1][0];
    s16x8 af[MH][2], bf[2][2];

    // ---------- q0: (A0,B0) -> acc[m][0..1]; stage Ah0'; wait covers Bh1(t) ----------
    #pragma unroll
    for (int m = 0; m < MH; ++m) {
      af[m][0] = *(const s16x8*)&A0[(arh + m * 32) * 64 + ck0];
      af[m][1] = *(const s16x8*)&A0[(arh + m * 32) * 64 + ck1];
    }
    #pragma unroll
    for (int n = 0; n < 2; ++n) {
      bf[n][0] = *(const s16x8*)&B0[(brh + n * 64) * 64 + ck0];
      bf[n][1] = *(const s16x8*)&B0[(brh + n * 64) * 64 + ck1];
    }
    if (pre) {
      stageAh(kt1, nb, 0);
      if constexpr (MW == 8) asm volatile("s_waitcnt vmcnt(4)" ::: "memory");
      else                   asm volatile("s_waitcnt vmcnt(2)" ::: "memory");
    } else {
      asm volatile("s_waitcnt vmcnt(0)" ::: "memory");
    }
    __builtin_amdgcn_s_barrier();
    __builtin_amdgcn_s_setprio(1);
    #pragma unroll
    for (int m = 0; m < MH; ++m)
      #pragma unroll
      for (int n = 0; n < 2; ++n) {
        acc[m][n] = __builtin_amdgcn_mfma_f32_16x16x32_bf16(af[m][0], bf[n][0], acc[m][n], 0, 0, 0);
        acc[m][n] = __builtin_amdgcn_mfma_f32_16x16x32_bf16(af[m][1], bf[n][1], acc[m][n], 0, 0, 0);
      }
    __builtin_amdgcn_s_setprio(0);

    // ---------- q1: (A0,B1) -> acc[m][2..3]; stage Bh0'; wait covers Ah1(t) ----------
    #pragma unroll
    for (int n = 0; n < 2; ++n) {
      bf[n][0] = *(const s16x8*)&B1[(brh + n * 64) * 64 + ck0];
      bf[n][1] = *(const s16x8*)&B1[(brh + n * 64) * 64 + ck1];
    }
    if (pre) {
      stageBh(kt1, nb, 0);
      if constexpr (MW == 8) asm volatile("s_waitcnt vmcnt(4)" ::: "memory");
      else                   asm volatile("s_waitcnt vmcnt(3)" ::: "memory");
    }
    __builtin_amdgcn_s_barrier();
    __builtin_amdgcn_s_setprio(1);
    #pragma unroll
    for (int m = 0; m < MH; ++m)
      #pragma unroll
      for (int n = 0; n < 2; ++n) {
        acc[m][2 + n] = __builtin_amdgcn_mfma_f32_16x16x32_bf16(af[m][0], bf[n][0], acc[m][2 + n], 0, 0, 0);
        acc[m][2 + n] = __builtin_amdgcn_mfma_f32_16x16x32_bf16(af[m][1], bf[n][1], acc[m][2 + n], 0, 0, 0);
      }
    __builtin_amdgcn_s_setprio(0);

    // ---------- q2: (A1,B1) -> acc[MH+m][2..3]; stage Bh1'; NO wait, NO barrier ----------
    #pragma unroll
    for (int m = 0; m < MH; ++m) {
      af[m][0] = *(const s16x8*)&A1[(arh + m * 32) * 64 + ck0];
      af[m][1] = *(const s16x8*)&A1[(arh + m * 32) * 64 + ck1];
    }
    if (pre) stageBh(kt1, nb, 1);
    __builtin_amdgcn_s_setprio(1);
    #pragma unroll
    for (int m = 0; m < MH; ++m)
      #pragma unroll
      for (int n = 0; n < 2; ++n) {
        acc[MH + m][2 + n] = __builtin_amdgcn_mfma_f32_16x16x32_bf16(af[m][0], bf[n][0], acc[MH + m][2 + n], 0, 0, 0);
        acc[MH + m][2 + n] = __builtin_amdgcn_mfma_f32_16x16x32_bf16(af[m][1], bf[n][1], acc[MH + m][2 + n], 0, 0, 0);
      }
    __builtin_amdgcn_s_setprio(0);

    // ---------- q3: (A1,B0) -> acc[MH+m][0..1]; stage Ah1'; wait covers Ah0'+Bh0' ----------
    #pragma unroll
    for (int n = 0; n < 2; ++n) {
      bf[n][0] = *(const s16x8*)&B0[(brh + n * 64) * 64 + ck0];
      bf[n][1] = *(const s16x8*)&B0[(brh + n * 64) * 64 + ck1];
    }
    if (pre) {
      stageAh(kt1, nb, 1);
      if constexpr (MW == 8) asm volatile("s_waitcnt vmcnt(4)" ::: "memory");
      else                   asm volatile("s_waitcnt vmcnt(3)" ::: "memory");
    }
    __builtin_amdgcn_s_barrier();
    __builtin_amdgcn_s_setprio(1);
    #pragma unroll
    for (int m = 0; m < MH; ++m)
      #pragma unroll
      for (int n = 0; n < 2; ++n) {
        acc[MH + m][n] = __builtin_amdgcn_mfma_f32_16x16x32_bf16(af[m][0], bf[n][0], acc[MH + m][n], 0, 0, 0);
        acc[MH + m][n] = __builtin_amdgcn_mfma_f32_16x16x32_bf16(af[m][1], bf[n][1], acc[MH + m][n], 0, 0, 0);
      }
    __builtin_amdgcn_s_setprio(0);
  }

  // epilogue: row = m0 + mi*32 + wm*16 + lg*4+jj ; col = n0 + ni*64 + wn*16 + l15
  const int rb = m0 + wm * 16;
  const int cb = n0 + wn * 16;
  if (QKVOUT && n0 >= VOFF) {
    #pragma unroll
    for (int mi = 0; mi < MW; ++mi)
      #pragma unroll
      for (int ni = 0; ni < 4; ++ni) {
        const int col = cb + ni * 64 + l15;
        const float bv = bias[col];
        const fx4 a = acc[mi][ni];
        ushort4 pk;
        pk.x = f2bf(a[0] + bv); pk.y = f2bf(a[1] + bv);
        pk.z = f2bf(a[2] + bv); pk.w = f2bf(a[3] + bv);
        const int d   = col - VOFF;
        const int kvp = d >> 8, dw = d & 255;
        const int row0 = rb + mi * 32 + lg * 4;      // key
        const int kt2 = row0 >> 5, kk = row0 & 31;
        const int kc = kk >> 3, k8 = kk & 7;
        *(ushort4*)&ctt[(size_t)kvp * 1048576 + (size_t)kt2 * 16384 + 8192
                        + kc * 2048 + dw * 8 + k8] = pk;
      }
  } else if (QKVOUT && n0 >= KOFF) {
    #pragma unroll
    for (int mi = 0; mi < MW; ++mi)
      #pragma unroll
      for (int ni = 0; ni < 4; ++ni) {
        const int col = cb + ni * 64 + l15;
        const int ccol = col - KOFF;
        const float bv = bias[col];
        const int kvp = ccol >> 8, cw = ccol & 255;
        const int cc = cw >> 3, cbt = cw & 7;
        const fx4 a = acc[mi][ni];
        #pragma unroll
        for (int jj = 0; jj < 4; ++jj) {
          const int row2 = rb + mi * 32 + lg * 4 + jj;   // key
          const int kt2 = row2 >> 5, kk = row2 & 31;
          ctt[(size_t)kvp * 1048576 + (size_t)kt2 * 16384 + cc * 256 + kk * 8 + cbt]
              = f2bf(a[jj] + bv);
        }
      }
  } else {
    #pragma unroll
    for (int mi = 0; mi < MW; ++mi)
      #pragma unroll
      for (int ni = 0; ni < 4; ++ni) {
        const int col = cb + ni * 64 + l15;
        const float bv = bias[col];
        const fx4 a = acc[mi][ni];
        #pragma unroll
        for (int jj = 0; jj < 4; ++jj) {
          const int row2 = rb + mi * 32 + lg * 4 + jj;
          const float v = a[jj] + bv;
          if (OUTBF16) ((unsigned short*)Cp)[(size_t)row2 * ldc + col] = f2bf(v);
          else         ((float*)Cp)[(size_t)row2 * ldc + col] = v;
        }
      }
  }
}

// Block = (pair, 64 q-rows), 4 waves (16 rows each, both diff components).
// K/V staged per 32-key tile via global_load_lds from the tile-contiguous ctt,
// double-buffered, ONE barrier per tile. All fragment ds_reads conflict-free.
__global__ __launch_bounds__(256, 2)
void attn_kernel(const unsigned short* __restrict__ qq,    // [TTOK][HIDN] bf16 Q
                 const unsigned short* __restrict__ ctt,   // tiled K/V
                 const float* __restrict__ lq1, const float* __restrict__ lk1,
                 const float* __restrict__ lq2, const float* __restrict__ lk2,
                 const float* __restrict__ subln,
                 unsigned short* __restrict__ attn_out)    // [TTOK][HIDN] bf16
{
  __shared__ __align__(16) unsigned short Sb[2][16384];    // [K 16KB][V 16KB]
  __shared__ __align__(16) unsigned short Pl[4][2][640];
  const int tid = threadIdx.x;
  const int lane = tid & 63, w = tid >> 6;
  const int l15 = lane & 15, lg = lane >> 4;

  // block decode: kvp -> XCD affinity, heavy q-blocks first
  const int bid = blockIdx.x;
  const int g = bid & 7, s = bid >> 3;
  const int kvp  = g >> 1;
  const int pair = kvp * 4 + (s & 3);
  const int qb   = 31 - ((s >> 2) << 1) - (g & 1);
  const int q0b  = qb * 64;
  const int q0w  = q0b + w * 16;
  const int nt   = 2 * qb + 2;

  const unsigned short* cbase = ctt + (size_t)kvp * 1048576;

  // stage tile kt (32KB linear) into Sb[buf]: 8 x global_load_lds(16B) per wave
  auto stage = [&](int kt, int buf) {
    const unsigned short* src = cbase + (size_t)kt * 16384;
    const int off = w * 512 + lane * 8;
    #pragma unroll
    for (int i = 0; i < 8; ++i) {
      const int o = i * 2048 + off;
      g2l16(src + o, &Sb[buf][o]);
    }
  };

  stage(0, 0);

  // lambda via wave-parallel dot
  float a1 = lq1[lane] * lk1[lane] + lq1[lane + 64] * lk1[lane + 64];
  float a2 = lq2[lane] * lk2[lane] + lq2[lane + 64] * lk2[lane + 64];
  #pragma unroll
  for (int sft = 1; sft < 64; sft <<= 1) { a1 += __shfl_xor(a1, sft); a2 += __shfl_xor(a2, sft); }
  const float lam = __expf(a1) - __expf(a2) + LAM_INIT;

  // Q fragments
  s16x8 qf0[4], qf1[4];
  {
    const unsigned short* qbp = qq + (size_t)(q0w + l15) * HIDN + pair * VD + lg * 8;
    #pragma unroll
    for (int kf = 0; kf < 4; ++kf) {
      qf0[kf] = *(const s16x8*)(qbp + kf * 32);
      qf1[kf] = *(const s16x8*)(qbp + DH + kf * 32);
    }
  }

  float mrun0 = -1e30f, mrun1 = -1e30f;
  float lrun0 = 0.f, lrun1 = 0.f;
  fx4 oacc0[16] = {}, oacc1[16] = {};
  unsigned short* pl0 = &Pl[w][0][0];
  unsigned short* pl1 = &Pl[w][1][0];
  const int q = q0w + l15;
  const int qmax = q0w + 15;

  for (int t = 0; t < nt; ++t) {
    __syncthreads();                      // stage(t) visible; buf[(t+1)&1] free
    if (t + 1 < nt) stage(t + 1, (t + 1) & 1);
    const int kb = t * 32;
    if (kb > qmax) continue;              // wave-uniform; still hits barrier next iter
    const unsigned short* Kl = Sb[t & 1];
    const unsigned short* Vl = Sb[t & 1] + 8192;

    // ---- QK^T swapped: S^T[key][q]
    fx4 s00 = {0,0,0,0}, s01 = {0,0,0,0}, s10 = {0,0,0,0}, s11 = {0,0,0,0};
    #pragma unroll
    for (int kf = 0; kf < 4; ++kf) {
      const int cc0 = kf * 4 + lg;        // comp0 chunks
      const int cc1 = 16 + kf * 4 + lg;   // comp1 chunks
      const s16x8 k00 = *(const s16x8*)&Kl[cc0 * 256 + l15 * 8];
      const s16x8 k01 = *(const s16x8*)&Kl[cc0 * 256 + (16 + l15) * 8];
      const s16x8 k10 = *(const s16x8*)&Kl[cc1 * 256 + l15 * 8];
      const s16x8 k11 = *(const s16x8*)&Kl[cc1 * 256 + (16 + l15) * 8];
      s00 = __builtin_amdgcn_mfma_f32_16x16x32_bf16(k00, qf0[kf], s00, 0, 0, 0);
      s01 = __builtin_amdgcn_mfma_f32_16x16x32_bf16(k01, qf0[kf], s01, 0, 0, 0);
      s10 = __builtin_amdgcn_mfma_f32_16x16x32_bf16(k10, qf1[kf], s10, 0, 0, 0);
      s11 = __builtin_amdgcn_mfma_f32_16x16x32_bf16(k11, qf1[kf], s11, 0, 0, 0);
    }

    // ---- mask + scale
    float v0[8], v1[8];
    #pragma unroll
    for (int j = 0; j < 4; ++j) {
      const int klo = kb + lg * 4 + j, khi = klo + 16;
      v0[j]     = (klo <= q) ? s00[j] * QKSCALE : -1e30f;
      v0[4 + j] = (khi <= q) ? s01[j] * QKSCALE : -1e30f;
      v1[j]     = (klo <= q) ? s10[j] * QKSCALE : -1e30f;
      v1[4 + j] = (khi <= q) ? s11[j] * QKSCALE : -1e30f;
    }
    // ---- tile max per comp
    float tm0 = fmaxf(fmaxf(fmaxf(v0[0],v0[1]),fmaxf(v0[2],v0[3])),
                      fmaxf(fmaxf(v0[4],v0[5]),fmaxf(v0[6],v0[7])));
    float tm1 = fmaxf(fmaxf(fmaxf(v1[0],v1[1]),fmaxf(v1[2],v1[3])),
                      fmaxf(fmaxf(v1[4],v1[5]),fmaxf(v1[6],v1[7])));
    tm0 = fmaxf(tm0, __shfl_xor(tm0, 16)); tm0 = fmaxf(tm0, __shfl_xor(tm0, 32));
    tm1 = fmaxf(tm1, __shfl_xor(tm1, 16)); tm1 = fmaxf(tm1, __shfl_xor(tm1, 32));

    // ---- defer-max rescale (rare)
    const bool need = (tm0 > mrun0 + RESCALE_THR) || (tm1 > mrun1 + RESCALE_THR);
    if (__any(need)) {
      const float mn0 = fmaxf(mrun0, tm0), mn1 = fmaxf(mrun1, tm1);
      const float fac0 = __expf(mrun0 - mn0), fac1 = __expf(mrun1 - mn1);
      mrun0 = mn0; mrun1 = mn1;
      lrun0 *= fac0; lrun1 *= fac1;
      #pragma unroll
      for (int jj = 0; jj < 4; ++jj) {
        const float fr0 = __shfl(fac0, lg * 4 + jj);
        const float fr1 = __shfl(fac1, lg * 4 + jj);
        #pragma unroll
        for (int nf = 0; nf < 16; ++nf) { oacc0[nf][jj] *= fr0; oacc1[nf][jj] *= fr1; }
      }
    }

    // ---- P = exp(v - mrun), pack bf16 -> per-wave LDS transpose
    {
      float ps0 = 0.f, ps1 = 0.f;
      ushort4 lo0, hi0, lo1, hi1;
      float p;
      p = __expf(v0[0]-mrun0); ps0 += p; lo0.x = f2bf(p);
      p = __expf(v0[1]-mrun0); ps0 += p; lo0.y = f2bf(p);
      p = __expf(v0[2]-mrun0); ps0 += p; lo0.z = f2bf(p);
      p = __expf(v0[3]-mrun0); ps0 += p; lo0.w = f2bf(p);
      p = __expf(v0[4]-mrun0); ps0 += p; hi0.x = f2bf(p);
      p = __expf(v0[5]-mrun0); ps0 += p; hi0.y = f2bf(p);
      p = __expf(v0[6]-mrun0); ps0 += p; hi0.z = f2bf(p);
      p = __expf(v0[7]-mrun0); ps0 += p; hi0.w = f2bf(p);
      p = __expf(v1[0]-mrun1); ps1 += p; lo1.x = f2bf(p);
      p = __expf(v1[1]-mrun1); ps1 += p; lo1.y = f2bf(p);
      p = __expf(v1[2]-mrun1); ps1 += p; lo1.z = f2bf(p);
      p = __expf(v1[3]-mrun1); ps1 += p; lo1.w = f2bf(p);
      p = __expf(v1[4]-mrun1); ps1 += p; hi1.x = f2bf(p);
      p = __expf(v1[5]-mrun1); ps1 += p; hi1.y = f2bf(p);
      p = __expf(v1[6]-mrun1); ps1 += p; hi1.z = f2bf(p);
      p = __expf(v1[7]-mrun1); ps1 += p; hi1.w = f2bf(p);
      lrun0 += ps0; lrun1 += ps1;
      *(ushort4*)&pl0[l15 * 40 + lg * 4]      = lo0;
      *(ushort4*)&pl0[l15 * 40 + 16 + lg * 4] = hi0;
      *(ushort4*)&pl1[l15 * 40 + lg * 4]      = lo1;
      *(ushort4*)&pl1[l15 * 40 + 16 + lg * 4] = hi1;
    }
    asm volatile("s_waitcnt lgkmcnt(0)" ::: "memory");
    __builtin_amdgcn_sched_barrier(0);

    // ---- PV from LDS V tile (conflict-free layout)
    const s16x8 pa0 = *(const s16x8*)&pl0[l15 * 40 + lg * 8];
    const s16x8 pa1 = *(const s16x8*)&pl1[l15 * 40 + lg * 8];
    #pragma unroll
    for (int nf = 0; nf < 16; ++nf) {
      const s16x8 vf = *(const s16x8*)&Vl[lg * 2048 + (nf * 16 + l15) * 8];
      oacc0[nf] = __builtin_amdgcn_mfma_f32_16x16x32_bf16(pa0, vf, oacc0[nf], 0, 0, 0);
      oacc1[nf] = __builtin_amdgcn_mfma_f32_16x16x32_bf16(pa1, vf, oacc1[nf], 0, 0, 0);
    }
  }

  // ---- finalize row sums
  lrun0 += __shfl_xor(lrun0, 16); lrun0 += __shfl_xor(lrun0, 32);
  lrun1 += __shfl_xor(lrun1, 16); lrun1 += __shfl_xor(lrun1, 32);

  float li0[4], li1[4];
  #pragma unroll
  for (int jj = 0; jj < 4; ++jj) {
    li0[jj] = 1.0f / __shfl(lrun0, lg * 4 + jj);
    li1[jj] = 1.0f / __shfl(lrun1, lg * 4 + jj);
  }

  // ---- combine, RMSNorm over 256, scale, store
  float ss[4] = {0.f, 0.f, 0.f, 0.f};
  #pragma unroll
  for (int nf = 0; nf < 16; ++nf)
    #pragma unroll
    for (int jj = 0; jj < 4; ++jj) {
      const float o = oacc0[nf][jj] * li0[jj] - lam * oacc1[nf][jj] * li1[jj];
      oacc0[nf][jj] = o;
      ss[jj] += o * o;
    }
  #pragma unroll
  for (int jj = 0; jj < 4; ++jj) {
    ss[jj] += __shfl_xor(ss[jj], 1);
    ss[jj] += __shfl_xor(ss[jj], 2);
    ss[jj] += __shfl_xor(ss[jj], 4);
    ss[jj] += __shfl_xor(ss[jj], 8);
    ss[jj] = rsqrtf(ss[jj] * (1.0f / 256.0f) + 1e-5f) * OML;
  }
  #pragma unroll
  for (int nf = 0; nf < 16; ++nf) {
    const int dcol = nf * 16 + l15;
    const float sw = subln[dcol];
    #pragma unroll
    for (int jj = 0; jj < 4; ++jj) {
      const int t = q0w + lg * 4 + jj;
      attn_out[(size_t)t * HIDN + pair * VD + dcol] = f2bf(oacc0[nf][jj] * ss[jj] * sw);
    }
  }
}

extern "C" void kernel_launch(void* const* d_in, const int* in_sizes, int n_in,
                              void* d_out, int out_size, void* d_ws, size_t ws_size,
                              hipStream_t stream) {
  (void)in_sizes; (void)n_in; (void)out_size; (void)ws_size;
  const float* hs     = (const float*)d_in[0];
  const float* wqkv_w = (const float*)d_in[1];
  const float* wqkv_b = (const float*)d_in[2];
  const float* lq1    = (const float*)d_in[3];
  const float* lk1    = (const float*)d_in[4];
  const float* lq2    = (const float*)d_in[5];
  const float* lk2    = (const float*)d_in[6];
  const float* subln  = (const float*)d_in[7];
  const float* out_w  = (const float*)d_in[8];
  const float* out_b  = (const float*)d_in[9];

  // ws layout (all bf16/ushort):
  //   qq [2048][4096] | ctt 4x1048576 | attn_out [2048][4096]
  //   hs_bf [2048*4096] | wqkv_bf [6144*4096] | outw_bf [4096*4096]   (~126 MB)
  unsigned short* qq       = (unsigned short*)d_ws;
  unsigned short* ctt      = qq + (size_t)TTOK * HIDN;
  unsigned short* attn_out = ctt + (size_t)4 * 1048576;
  unsigned short* hs_bf    = attn_out + (size_t)TTOK * HIDN;
  unsigned short* wqkv_bf  = hs_bf + (size_t)TTOK * HIDN;
  unsigned short* outw_bf  = wqkv_bf + (size_t)OPD * HIDN;

  const int nb0 = (TTOK * HIDN) >> 11;          // 4096
  const int nb1 = (OPD * HIDN) >> 11;           // 12288
  const int nb2 = (HIDN * HIDN) >> 11;          // 8192
  cvt3<<<dim3(nb0 + nb1 + nb2), 256, 0, stream>>>(
      hs, hs_bf, nb0, wqkv_w, wqkv_bf, nb1, out_w, outw_bf);

  // GEMM1: 256x256 tile; Q -> qq row-major; K/V -> ctt tiled (region-aligned blocks)
  gemm_8ph<8, true, true><<<dim3(OPD / 256, TTOK / 256), 512, 0, stream>>>(
      hs_bf, wqkv_bf, wqkv_b, qq, ctt, HIDN, HIDN, HIDN, HIDN);

  // Attention + combine + RMSNorm -> attn_out (bf16)
  attn_kernel<<<dim3(512), 256, 0, stream>>>(
      qq, ctt, lq1, lk1, lq2, lk2, subln, attn_out);

  // GEMM2: 128x256 tile; out = attn_out @ out_w^T + out_b  (fp32 out)
  gemm_8ph<4, false, false><<<dim3(HIDN / 256, TTOK / 128), 512, 0, stream>>>(
      attn_out, outw_bf, out_b, d_out, nullptr, HIDN, HIDN, HIDN, HIDN);
}

// Round 11
// 334.081 us; speedup vs baseline: 1.2534x; 1.0689x over previous
//
#include <hip/hip_runtime.h>

#define TTOK 2048
#define HIDN 4096
#define OPD  6144
#define DH   128
#define VD   256
#define KOFF 4096
#define VOFF 5120

typedef short  s16x8 __attribute__((ext_vector_type(8)));
typedef unsigned short u16x8 __attribute__((ext_vector_type(8)));
typedef float  fx4   __attribute__((ext_vector_type(4)));

constexpr float LAM_INIT = 0.7455692280263534f;
constexpr float OML      = 1.0f - LAM_INIT;          // (1 - lambda_init)
constexpr float QKSCALE  = 0.08838834764831845f;     // 128^-0.5
constexpr float RESCALE_THR = 8.0f;

__device__ __forceinline__ unsigned short f2bf(float f) {
  unsigned int u = __builtin_bit_cast(unsigned int, f);
  u += 0x7fffu + ((u >> 16) & 1u);   // RNE
  return (unsigned short)(u >> 16);
}

__device__ __forceinline__ void g2l16(const void* gsrc, void* ldst) {
  __builtin_amdgcn_global_load_lds(
      (const __attribute__((address_space(1))) unsigned int*)gsrc,
      (__attribute__((address_space(3))) unsigned int*)ldst, 16, 0, 0);
}

// fp32 -> bf16 bulk convert, 3 tensors, 2048 elems/block (all sizes % 2048 == 0)
__global__ __launch_bounds__(256)
void cvt3(const float* __restrict__ s0, unsigned short* __restrict__ d0, int nb0,
          const float* __restrict__ s1, unsigned short* __restrict__ d1, int nb1,
          const float* __restrict__ s2, unsigned short* __restrict__ d2)
{
  const int b = blockIdx.x;
  const float* s; unsigned short* d; int base;
  if (b < nb0)            { s = s0; d = d0; base = b << 11; }
  else if (b < nb0 + nb1) { s = s1; d = d1; base = (b - nb0) << 11; }
  else                    { s = s2; d = d2; base = (b - nb0 - nb1) << 11; }
  const int i = base + (int)threadIdx.x * 8;
  const float4 a0 = *(const float4*)(s + i);
  const float4 a1 = *(const float4*)(s + i + 4);
  u16x8 v;
  v[0]=f2bf(a0.x); v[1]=f2bf(a0.y); v[2]=f2bf(a0.z); v[3]=f2bf(a0.w);
  v[4]=f2bf(a1.x); v[5]=f2bf(a1.y); v[6]=f2bf(a1.z); v[7]=f2bf(a1.w);
  *(u16x8*)(d + i) = v;
}

// out = p[0] + p[1] + bias  (split-K reduce, fp32, float4)
__global__ __launch_bounds__(256)
void reduce2(const float* __restrict__ p, const float* __restrict__ bias,
             float* __restrict__ out)
{
  const size_t i = ((size_t)blockIdx.x * 256 + threadIdx.x) * 4;
  const int col = (int)(i & (HIDN - 1));
  const float4 a = *(const float4*)(p + i);
  const float4 b = *(const float4*)(p + (size_t)TTOK * HIDN + i);
  const float4 c = *(const float4*)(bias + col);
  float4 r;
  r.x = a.x + b.x + c.x; r.y = a.y + b.y + c.y;
  r.z = a.z + b.z + c.z; r.w = a.w + b.w + c.w;
  *(float4*)(out + i) = r;
}

// C[M,N] = A[M,K] * B[N,K]^T (+ bias), bf16 in.  8 waves (2M x 4N) interleaved.
// BK=64, 2 K-tile LDS dbuf in row-halves.  Phases (A0B0)(A0B1)(A1B1)(A1B0);
// B0 frags HELD IN REGISTERS across the K-tile (bf0 separate from bf1) so q3
// does no LDS reads -> its MFMA runs BEFORE its vmcnt wait, covering the Ah1'
// stage latency.  Steady waits vmcnt(4) at q0/q1/q3 (FIFO: each awaited half
// is >=2 phases old); vmcnt(0) only prologue + last tile.  Barriers only after
// waits (3/K-tile).  LDS XOR-swizzle (pre-swizzled global source + swizzled
// ds_read col) keeps reads conflict-free.
// MODE 0: GEMM1 — Q cols -> Cp row-major bf16, K/V cols -> ctt tiled.
// MODE 1: split-K partial — fp32, no bias, to Cp + z*M*N; kOff = z*K.
template<int MW, int MODE>
__global__ __launch_bounds__(512, 2)
void gemm_8ph(const unsigned short* __restrict__ A, const unsigned short* __restrict__ B,
              const float* __restrict__ bias, void* __restrict__ Cp,
              unsigned short* __restrict__ ctt, int K, int lda, int ldb, int ldc)
{
  constexpr int BM   = MW * 32;          // 256
  constexpr int MH   = MW / 2;           // 4
  constexpr int ALD2 = MW / 4;           // 2
  __shared__ __align__(16) unsigned short As[2][2][(BM / 2) * 64];
  __shared__ __align__(16) unsigned short Bs[2][2][128 * 64];

  const int tid  = threadIdx.x;
  const int lane = tid & 63, wid = tid >> 6;
  const int wm = wid >> 2, wn = wid & 3;            // 2 x 4 wave grid
  const int m0 = blockIdx.y * BM, n0 = blockIdx.x * 256;
  const int l15 = lane & 15, lg = lane >> 4;
  const int kOff = (MODE == 1) ? blockIdx.z * K : 0;

  // staging: linear LDS dest, inverse-swizzled global source
  const int srow = tid >> 3;                                  // 0..63
  const int scol = ((tid & 7) ^ ((tid >> 3) & 7)) << 3;
  // fragment reads: swizzled col constants (row&7 == l15&7 for all frags)
  const int rsw = (l15 & 7) << 3;
  const int ck0 = (lg * 8) ^ rsw;
  const int ck1 = (32 + lg * 8) ^ rsw;
  const int arh = wm * 16 + l15;        // + mi_local*32 within half
  const int brh = wn * 16 + l15;        // + ni_local*64 within half

  auto stageAh = [&](int kt, int buf, int h) {
    #pragma unroll
    for (int i = 0; i < ALD2; ++i)
      g2l16(A + (size_t)(m0 + h * (BM / 2) + i * 64 + srow) * lda + kOff + kt + scol,
            &As[buf][h][(i * 512 + tid) * 8]);
  };
  auto stageBh = [&](int kt, int buf, int h) {
    #pragma unroll
    for (int i = 0; i < 2; ++i)
      g2l16(B + (size_t)(n0 + h * 128 + i * 64 + srow) * ldb + kOff + kt + scol,
            &Bs[buf][h][(i * 512 + tid) * 8]);
  };

  fx4 acc[MW][4] = {};

  const int nk = K >> 6;
  stageAh(0, 0, 0); stageBh(0, 0, 0); stageBh(0, 0, 1); stageAh(0, 0, 1);
  asm volatile("s_waitcnt vmcnt(0)" ::: "memory");
  __builtin_amdgcn_s_barrier();

  for (int t = 0; t < nk; ++t) {
    const int buf = t & 1, nb = buf ^ 1;
    const int kt1 = (t + 1) << 6;
    const bool pre = (t + 1) < nk;
    const unsigned short* A0 = &As[buf][0][0];
    const unsigned short* A1 = &As[buf][1][0];
    const unsigned short* B0 = &Bs[buf][0][0];
    const unsigned short* B1 = &Bs[buf][1][0];
    s16x8 af[MH][2], bf0[2][2], bf1[2][2];

    // ---------- q0: (A0,B0) -> acc[m][0..1]; stage Ah0'; wait drains Bh1(t) ----------
    #pragma unroll
    for (int m = 0; m < MH; ++m) {
      af[m][0] = *(const s16x8*)&A0[(arh + m * 32) * 64 + ck0];
      af[m][1] = *(const s16x8*)&A0[(arh + m * 32) * 64 + ck1];
    }
    #pragma unroll
    for (int n = 0; n < 2; ++n) {
      bf0[n][0] = *(const s16x8*)&B0[(brh + n * 64) * 64 + ck0];
      bf0[n][1] = *(const s16x8*)&B0[(brh + n * 64) * 64 + ck1];
    }
    if (pre) {
      stageAh(kt1, nb, 0);
      asm volatile("s_waitcnt vmcnt(4)" ::: "memory");
    } else {
      asm volatile("s_waitcnt vmcnt(0)" ::: "memory");
    }
    __builtin_amdgcn_s_barrier();
    __builtin_amdgcn_s_setprio(1);
    #pragma unroll
    for (int m = 0; m < MH; ++m)
      #pragma unroll
      for (int n = 0; n < 2; ++n) {
        acc[m][n] = __builtin_amdgcn_mfma_f32_16x16x32_bf16(af[m][0], bf0[n][0], acc[m][n], 0, 0, 0);
        acc[m][n] = __builtin_amdgcn_mfma_f32_16x16x32_bf16(af[m][1], bf0[n][1], acc[m][n], 0, 0, 0);
      }
    __builtin_amdgcn_s_setprio(0);

    // ---------- q1: (A0,B1) -> acc[m][2..3]; stage Bh0'; wait drains Ah1(t) ----------
    #pragma unroll
    for (int n = 0; n < 2; ++n) {
      bf1[n][0] = *(const s16x8*)&B1[(brh + n * 64) * 64 + ck0];
      bf1[n][1] = *(const s16x8*)&B1[(brh + n * 64) * 64 + ck1];
    }
    if (pre) {
      stageBh(kt1, nb, 0);
      asm volatile("s_waitcnt vmcnt(4)" ::: "memory");
    }
    __builtin_amdgcn_s_barrier();
    __builtin_amdgcn_s_setprio(1);
    #pragma unroll
    for (int m = 0; m < MH; ++m)
      #pragma unroll
      for (int n = 0; n < 2; ++n) {
        acc[m][2 + n] = __builtin_amdgcn_mfma_f32_16x16x32_bf16(af[m][0], bf1[n][0], acc[m][2 + n], 0, 0, 0);
        acc[m][2 + n] = __builtin_amdgcn_mfma_f32_16x16x32_bf16(af[m][1], bf1[n][1], acc[m][2 + n], 0, 0, 0);
      }
    __builtin_amdgcn_s_setprio(0);

    // ---------- q2: (A1,B1) -> acc[MH+m][2..3]; stage Bh1'; no wait, no barrier ----------
    #pragma unroll
    for (int m = 0; m < MH; ++m) {
      af[m][0] = *(const s16x8*)&A1[(arh + m * 32) * 64 + ck0];
      af[m][1] = *(const s16x8*)&A1[(arh + m * 32) * 64 + ck1];
    }
    if (pre) stageBh(kt1, nb, 1);
    __builtin_amdgcn_s_setprio(1);
    #pragma unroll
    for (int m = 0; m < MH; ++m)
      #pragma unroll
      for (int n = 0; n < 2; ++n) {
        acc[MH + m][2 + n] = __builtin_amdgcn_mfma_f32_16x16x32_bf16(af[m][0], bf1[n][0], acc[MH + m][2 + n], 0, 0, 0);
        acc[MH + m][2 + n] = __builtin_amdgcn_mfma_f32_16x16x32_bf16(af[m][1], bf1[n][1], acc[MH + m][2 + n], 0, 0, 0);
      }
    __builtin_amdgcn_s_setprio(0);

    // ---------- q3: (A1,B0) from REGISTERS -> acc[MH+m][0..1]; stage Ah1';
    //             MFMA first (no LDS dep), then wait (drains Ah0'+Bh0') ----------
    if (pre) stageAh(kt1, nb, 1);
    __builtin_amdgcn_s_setprio(1);
    #pragma unroll
    for (int m = 0; m < MH; ++m)
      #pragma unroll
      for (int n = 0; n < 2; ++n) {
        acc[MH + m][n] = __builtin_amdgcn_mfma_f32_16x16x32_bf16(af[m][0], bf0[n][0], acc[MH + m][n], 0, 0, 0);
        acc[MH + m][n] = __builtin_amdgcn_mfma_f32_16x16x32_bf16(af[m][1], bf0[n][1], acc[MH + m][n], 0, 0, 0);
      }
    __builtin_amdgcn_s_setprio(0);
    if (pre) asm volatile("s_waitcnt vmcnt(4)" ::: "memory");
    __builtin_amdgcn_s_barrier();
  }

  // epilogue: row = m0 + mi*32 + wm*16 + lg*4+jj ; col = n0 + ni*64 + wn*16 + l15
  const int rb = m0 + wm * 16;
  const int cb = n0 + wn * 16;
  if (MODE == 1) {
    float* P = (float*)Cp + (size_t)blockIdx.z * (size_t)gridDim.y * BM * ldc;
    #pragma unroll
    for (int mi = 0; mi < MW; ++mi)
      #pragma unroll
      for (int ni = 0; ni < 4; ++ni) {
        const int col = cb + ni * 64 + l15;
        const fx4 a = acc[mi][ni];
        #pragma unroll
        for (int jj = 0; jj < 4; ++jj)
          P[(size_t)(rb + mi * 32 + lg * 4 + jj) * ldc + col] = a[jj];
      }
  } else if (n0 >= VOFF) {
    #pragma unroll
    for (int mi = 0; mi < MW; ++mi)
      #pragma unroll
      for (int ni = 0; ni < 4; ++ni) {
        const int col = cb + ni * 64 + l15;
        const float bv = bias[col];
        const fx4 a = acc[mi][ni];
        ushort4 pk;
        pk.x = f2bf(a[0] + bv); pk.y = f2bf(a[1] + bv);
        pk.z = f2bf(a[2] + bv); pk.w = f2bf(a[3] + bv);
        const int d   = col - VOFF;
        const int kvp = d >> 8, dw = d & 255;
        const int row0 = rb + mi * 32 + lg * 4;      // key
        const int kt2 = row0 >> 5, kk = row0 & 31;
        const int kc = kk >> 3, k8 = kk & 7;
        *(ushort4*)&ctt[(size_t)kvp * 1048576 + (size_t)kt2 * 16384 + 8192
                        + kc * 2048 + dw * 8 + k8] = pk;
      }
  } else if (n0 >= KOFF) {
    #pragma unroll
    for (int mi = 0; mi < MW; ++mi)
      #pragma unroll
      for (int ni = 0; ni < 4; ++ni) {
        const int col = cb + ni * 64 + l15;
        const int ccol = col - KOFF;
        const float bv = bias[col];
        const int kvp = ccol >> 8, cw = ccol & 255;
        const int cc = cw >> 3, cbt = cw & 7;
        const fx4 a = acc[mi][ni];
        #pragma unroll
        for (int jj = 0; jj < 4; ++jj) {
          const int row2 = rb + mi * 32 + lg * 4 + jj;   // key
          const int kt2 = row2 >> 5, kk = row2 & 31;
          ctt[(size_t)kvp * 1048576 + (size_t)kt2 * 16384 + cc * 256 + kk * 8 + cbt]
              = f2bf(a[jj] + bv);
        }
      }
  } else {
    #pragma unroll
    for (int mi = 0; mi < MW; ++mi)
      #pragma unroll
      for (int ni = 0; ni < 4; ++ni) {
        const int col = cb + ni * 64 + l15;
        const float bv = bias[col];
        const fx4 a = acc[mi][ni];
        #pragma unroll
        for (int jj = 0; jj < 4; ++jj) {
          const int row2 = rb + mi * 32 + lg * 4 + jj;
          ((unsigned short*)Cp)[(size_t)row2 * ldc + col] = f2bf(a[jj] + bv);
        }
      }
  }
}

// Block = (pair, 64 q-rows), 4 waves (16 rows each, both diff components).
// K/V staged per 32-key tile via global_load_lds from the tile-contiguous ctt,
// double-buffered, ONE barrier per tile. All fragment ds_reads conflict-free.
__global__ __launch_bounds__(256, 2)
void attn_kernel(const unsigned short* __restrict__ qq,    // [TTOK][HIDN] bf16 Q
                 const unsigned short* __restrict__ ctt,   // tiled K/V
                 const float* __restrict__ lq1, const float* __restrict__ lk1,
                 const float* __restrict__ lq2, const float* __restrict__ lk2,
                 const float* __restrict__ subln,
                 unsigned short* __restrict__ attn_out)    // [TTOK][HIDN] bf16
{
  __shared__ __align__(16) unsigned short Sb[2][16384];    // [K 16KB][V 16KB]
  __shared__ __align__(16) unsigned short Pl[4][2][640];
  const int tid = threadIdx.x;
  const int lane = tid & 63, w = tid >> 6;
  const int l15 = lane & 15, lg = lane >> 4;

  // block decode: kvp -> XCD affinity, heavy q-blocks first
  const int bid = blockIdx.x;
  const int g = bid & 7, s = bid >> 3;
  const int kvp  = g >> 1;
  const int pair = kvp * 4 + (s & 3);
  const int qb   = 31 - ((s >> 2) << 1) - (g & 1);
  const int q0b  = qb * 64;
  const int q0w  = q0b + w * 16;
  const int nt   = 2 * qb + 2;

  const unsigned short* cbase = ctt + (size_t)kvp * 1048576;

  // stage tile kt (32KB linear) into Sb[buf]: 8 x global_load_lds(16B) per wave
  auto stage = [&](int kt, int buf) {
    const unsigned short* src = cbase + (size_t)kt * 16384;
    const int off = w * 512 + lane * 8;
    #pragma unroll
    for (int i = 0; i < 8; ++i) {
      const int o = i * 2048 + off;
      g2l16(src + o, &Sb[buf][o]);
    }
  };

  stage(0, 0);

  // lambda via wave-parallel dot
  float a1 = lq1[lane] * lk1[lane] + lq1[lane + 64] * lk1[lane + 64];
  float a2 = lq2[lane] * lk2[lane] + lq2[lane + 64] * lk2[lane + 64];
  #pragma unroll
  for (int sft = 1; sft < 64; sft <<= 1) { a1 += __shfl_xor(a1, sft); a2 += __shfl_xor(a2, sft); }
  const float lam = __expf(a1) - __expf(a2) + LAM_INIT;

  // Q fragments
  s16x8 qf0[4], qf1[4];
  {
    const unsigned short* qbp = qq + (size_t)(q0w + l15) * HIDN + pair * VD + lg * 8;
    #pragma unroll
    for (int kf = 0; kf < 4; ++kf) {
      qf0[kf] = *(const s16x8*)(qbp + kf * 32);
      qf1[kf] = *(const s16x8*)(qbp + DH + kf * 32);
    }
  }

  float mrun0 = -1e30f, mrun1 = -1e30f;
  float lrun0 = 0.f, lrun1 = 0.f;
  fx4 oacc0[16] = {}, oacc1[16] = {};
  unsigned short* pl0 = &Pl[w][0][0];
  unsigned short* pl1 = &Pl[w][1][0];
  const int q = q0w + l15;
  const int qmax = q0w + 15;

  for (int t = 0; t < nt; ++t) {
    __syncthreads();                      // stage(t) visible; buf[(t+1)&1] free
    if (t + 1 < nt) stage(t + 1, (t + 1) & 1);
    const int kb = t * 32;
    if (kb > qmax) continue;              // wave-uniform; still hits barrier next iter
    const unsigned short* Kl = Sb[t & 1];
    const unsigned short* Vl = Sb[t & 1] + 8192;

    // ---- QK^T swapped: S^T[key][q]
    fx4 s00 = {0,0,0,0}, s01 = {0,0,0,0}, s10 = {0,0,0,0}, s11 = {0,0,0,0};
    #pragma unroll
    for (int kf = 0; kf < 4; ++kf) {
      const int cc0 = kf * 4 + lg;        // comp0 chunks
      const int cc1 = 16 + kf * 4 + lg;   // comp1 chunks
      const s16x8 k00 = *(const s16x8*)&Kl[cc0 * 256 + l15 * 8];
      const s16x8 k01 = *(const s16x8*)&Kl[cc0 * 256 + (16 + l15) * 8];
      const s16x8 k10 = *(const s16x8*)&Kl[cc1 * 256 + l15 * 8];
      const s16x8 k11 = *(const s16x8*)&Kl[cc1 * 256 + (16 + l15) * 8];
      s00 = __builtin_amdgcn_mfma_f32_16x16x32_bf16(k00, qf0[kf], s00, 0, 0, 0);
      s01 = __builtin_amdgcn_mfma_f32_16x16x32_bf16(k01, qf0[kf], s01, 0, 0, 0);
      s10 = __builtin_amdgcn_mfma_f32_16x16x32_bf16(k10, qf1[kf], s10, 0, 0, 0);
      s11 = __builtin_amdgcn_mfma_f32_16x16x32_bf16(k11, qf1[kf], s11, 0, 0, 0);
    }

    // ---- mask + scale
    float v0[8], v1[8];
    #pragma unroll
    for (int j = 0; j < 4; ++j) {
      const int klo = kb + lg * 4 + j, khi = klo + 16;
      v0[j]     = (klo <= q) ? s00[j] * QKSCALE : -1e30f;
      v0[4 + j] = (khi <= q) ? s01[j] * QKSCALE : -1e30f;
      v1[j]     = (klo <= q) ? s10[j] * QKSCALE : -1e30f;
      v1[4 + j] = (khi <= q) ? s11[j] * QKSCALE : -1e30f;
    }
    // ---- tile max per comp
    float tm0 = fmaxf(fmaxf(fmaxf(v0[0],v0[1]),fmaxf(v0[2],v0[3])),
                      fmaxf(fmaxf(v0[4],v0[5]),fmaxf(v0[6],v0[7])));
    float tm1 = fmaxf(fmaxf(fmaxf(v1[0],v1[1]),fmaxf(v1[2],v1[3])),
                      fmaxf(fmaxf(v1[4],v1[5]),fmaxf(v1[6],v1[7])));
    tm0 = fmaxf(tm0, __shfl_xor(tm0, 16)); tm0 = fmaxf(tm0, __shfl_xor(tm0, 32));
    tm1 = fmaxf(tm1, __shfl_xor(tm1, 16)); tm1 = fmaxf(tm1, __shfl_xor(tm1, 32));

    // ---- defer-max rescale (rare)
    const bool need = (tm0 > mrun0 + RESCALE_THR) || (tm1 > mrun1 + RESCALE_THR);
    if (__any(need)) {
      const float mn0 = fmaxf(mrun0, tm0), mn1 = fmaxf(mrun1, tm1);
      const float fac0 = __expf(mrun0 - mn0), fac1 = __expf(mrun1 - mn1);
      mrun0 = mn0; mrun1 = mn1;
      lrun0 *= fac0; lrun1 *= fac1;
      #pragma unroll
      for (int jj = 0; jj < 4; ++jj) {
        const float fr0 = __shfl(fac0, lg * 4 + jj);
        const float fr1 = __shfl(fac1, lg * 4 + jj);
        #pragma unroll
        for (int nf = 0; nf < 16; ++nf) { oacc0[nf][jj] *= fr0; oacc1[nf][jj] *= fr1; }
      }
    }

    // ---- P = exp(v - mrun), pack bf16 -> per-wave LDS transpose
    {
      float ps0 = 0.f, ps1 = 0.f;
      ushort4 lo0, hi0, lo1, hi1;
      float p;
      p = __expf(v0[0]-mrun0); ps0 += p; lo0.x = f2bf(p);
      p = __expf(v0[1]-mrun0); ps0 += p; lo0.y = f2bf(p);
      p = __expf(v0[2]-mrun0); ps0 += p; lo0.z = f2bf(p);
      p = __expf(v0[3]-mrun0); ps0 += p; lo0.w = f2bf(p);
      p = __expf(v0[4]-mrun0); ps0 += p; hi0.x = f2bf(p);
      p = __expf(v0[5]-mrun0); ps0 += p; hi0.y = f2bf(p);
      p = __expf(v0[6]-mrun0); ps0 += p; hi0.z = f2bf(p);
      p = __expf(v0[7]-mrun0); ps0 += p; hi0.w = f2bf(p);
      p = __expf(v1[0]-mrun1); ps1 += p; lo1.x = f2bf(p);
      p = __expf(v1[1]-mrun1); ps1 += p; lo1.y = f2bf(p);
      p = __expf(v1[2]-mrun1); ps1 += p; lo1.z = f2bf(p);
      p = __expf(v1[3]-mrun1); ps1 += p; lo1.w = f2bf(p);
      p = __expf(v1[4]-mrun1); ps1 += p; hi1.x = f2bf(p);
      p = __expf(v1[5]-mrun1); ps1 += p; hi1.y = f2bf(p);
      p = __expf(v1[6]-mrun1); ps1 += p; hi1.z = f2bf(p);
      p = __expf(v1[7]-mrun1); ps1 += p; hi1.w = f2bf(p);
      lrun0 += ps0; lrun1 += ps1;
      *(ushort4*)&pl0[l15 * 40 + lg * 4]      = lo0;
      *(ushort4*)&pl0[l15 * 40 + 16 + lg * 4] = hi0;
      *(ushort4*)&pl1[l15 * 40 + lg * 4]      = lo1;
      *(ushort4*)&pl1[l15 * 40 + 16 + lg * 4] = hi1;
    }
    asm volatile("s_waitcnt lgkmcnt(0)" ::: "memory");
    __builtin_amdgcn_sched_barrier(0);

    // ---- PV from LDS V tile (conflict-free layout)
    const s16x8 pa0 = *(const s16x8*)&pl0[l15 * 40 + lg * 8];
    const s16x8 pa1 = *(const s16x8*)&pl1[l15 * 40 + lg * 8];
    #pragma unroll
    for (int nf = 0; nf < 16; ++nf) {
      const s16x8 vf = *(const s16x8*)&Vl[lg * 2048 + (nf * 16 + l15) * 8];
      oacc0[nf] = __builtin_amdgcn_mfma_f32_16x16x32_bf16(pa0, vf, oacc0[nf], 0, 0, 0);
      oacc1[nf] = __builtin_amdgcn_mfma_f32_16x16x32_bf16(pa1, vf, oacc1[nf], 0, 0, 0);
    }
  }

  // ---- finalize row sums
  lrun0 += __shfl_xor(lrun0, 16); lrun0 += __shfl_xor(lrun0, 32);
  lrun1 += __shfl_xor(lrun1, 16); lrun1 += __shfl_xor(lrun1, 32);

  float li0[4], li1[4];
  #pragma unroll
  for (int jj = 0; jj < 4; ++jj) {
    li0[jj] = 1.0f / __shfl(lrun0, lg * 4 + jj);
    li1[jj] = 1.0f / __shfl(lrun1, lg * 4 + jj);
  }

  // ---- combine, RMSNorm over 256, scale, store
  float ss[4] = {0.f, 0.f, 0.f, 0.f};
  #pragma unroll
  for (int nf = 0; nf < 16; ++nf)
    #pragma unroll
    for (int jj = 0; jj < 4; ++jj) {
      const float o = oacc0[nf][jj] * li0[jj] - lam * oacc1[nf][jj] * li1[jj];
      oacc0[nf][jj] = o;
      ss[jj] += o * o;
    }
  #pragma unroll
  for (int jj = 0; jj < 4; ++jj) {
    ss[jj] += __shfl_xor(ss[jj], 1);
    ss[jj] += __shfl_xor(ss[jj], 2);
    ss[jj] += __shfl_xor(ss[jj], 4);
    ss[jj] += __shfl_xor(ss[jj], 8);
    ss[jj] = rsqrtf(ss[jj] * (1.0f / 256.0f) + 1e-5f) * OML;
  }
  #pragma unroll
  for (int nf = 0; nf < 16; ++nf) {
    const int dcol = nf * 16 + l15;
    const float sw = subln[dcol];
    #pragma unroll
    for (int jj = 0; jj < 4; ++jj) {
      const int t = q0w + lg * 4 + jj;
      attn_out[(size_t)t * HIDN + pair * VD + dcol] = f2bf(oacc0[nf][jj] * ss[jj] * sw);
    }
  }
}

extern "C" void kernel_launch(void* const* d_in, const int* in_sizes, int n_in,
                              void* d_out, int out_size, void* d_ws, size_t ws_size,
                              hipStream_t stream) {
  (void)in_sizes; (void)n_in; (void)out_size; (void)ws_size;
  const float* hs     = (const float*)d_in[0];
  const float* wqkv_w = (const float*)d_in[1];
  const float* wqkv_b = (const float*)d_in[2];
  const float* lq1    = (const float*)d_in[3];
  const float* lk1    = (const float*)d_in[4];
  const float* lq2    = (const float*)d_in[5];
  const float* lk2    = (const float*)d_in[6];
  const float* subln  = (const float*)d_in[7];
  const float* out_w  = (const float*)d_in[8];
  const float* out_b  = (const float*)d_in[9];

  // ws layout (all bf16/ushort):
  //   qq [2048][4096] | ctt 4x1048576 | attn_out [2048][4096]
  //   hs_bf [2048*4096] | wqkv_bf [6144*4096] | outw_bf [4096*4096]   (~140 MB)
  // hs_bf+wqkv_bf (66 MB, dead after GEMM1) are overlaid by the 64 MB split-K
  // partial buffer during GEMM2.
  unsigned short* qq       = (unsigned short*)d_ws;
  unsigned short* ctt      = qq + (size_t)TTOK * HIDN;
  unsigned short* attn_out = ctt + (size_t)4 * 1048576;
  unsigned short* hs_bf    = attn_out + (size_t)TTOK * HIDN;
  unsigned short* wqkv_bf  = hs_bf + (size_t)TTOK * HIDN;
  unsigned short* outw_bf  = wqkv_bf + (size_t)OPD * HIDN;
  float*          partial  = (float*)hs_bf;   // 2 x [2048][4096] fp32

  const int nb0 = (TTOK * HIDN) >> 11;          // 4096
  const int nb1 = (OPD * HIDN) >> 11;           // 12288
  const int nb2 = (HIDN * HIDN) >> 11;          // 8192
  cvt3<<<dim3(nb0 + nb1 + nb2), 256, 0, stream>>>(
      hs, hs_bf, nb0, wqkv_w, wqkv_bf, nb1, out_w, outw_bf);

  // GEMM1: 256x256 tile; Q -> qq row-major; K/V -> ctt tiled (region-aligned blocks)
  gemm_8ph<8, 0><<<dim3(OPD / 256, TTOK / 256), 512, 0, stream>>>(
      hs_bf, wqkv_bf, wqkv_b, qq, ctt, HIDN, HIDN, HIDN, HIDN);

  // Attention + combine + RMSNorm -> attn_out (bf16)
  attn_kernel<<<dim3(512), 256, 0, stream>>>(
      qq, ctt, lq1, lk1, lq2, lk2, subln, attn_out);

  // GEMM2 split-K: 256 blocks (16 x 8 x 2), each K=2048 -> fp32 partials
  gemm_8ph<8, 1><<<dim3(HIDN / 256, TTOK / 256, 2), 512, 0, stream>>>(
      attn_out, outw_bf, nullptr, partial, nullptr, HIDN / 2, HIDN, HIDN, HIDN);

  // out = partial0 + partial1 + out_b
  reduce2<<<dim3((TTOK * HIDN) / 1024), 256, 0, stream>>>(
      partial, out_b, (float*)d_out);
}

// Round 12
// 330.741 us; speedup vs baseline: 1.2661x; 1.0101x over previous
//
#include <hip/hip_runtime.h>

#define TTOK 2048
#define HIDN 4096
#define OPD  6144
#define DH   128
#define VD   256
#define KOFF 4096
#define VOFF 5120

typedef short  s16x8 __attribute__((ext_vector_type(8)));
typedef unsigned short u16x8 __attribute__((ext_vector_type(8)));
typedef float  fx4   __attribute__((ext_vector_type(4)));

constexpr float LAM_INIT = 0.7455692280263534f;
constexpr float OML      = 1.0f - LAM_INIT;          // (1 - lambda_init)
constexpr float QKSCALE  = 0.08838834764831845f;     // 128^-0.5
constexpr float RESCALE_THR = 8.0f;

__device__ __forceinline__ unsigned short f2bf(float f) {
  unsigned int u = __builtin_bit_cast(unsigned int, f);
  u += 0x7fffu + ((u >> 16) & 1u);   // RNE
  return (unsigned short)(u >> 16);
}

__device__ __forceinline__ void g2l16(const void* gsrc, void* ldst) {
  __builtin_amdgcn_global_load_lds(
      (const __attribute__((address_space(1))) unsigned int*)gsrc,
      (__attribute__((address_space(3))) unsigned int*)ldst, 16, 0, 0);
}

// fp32 -> bf16 bulk convert, 3 tensors, 2048 elems/block (all sizes % 2048 == 0)
__global__ __launch_bounds__(256)
void cvt3(const float* __restrict__ s0, unsigned short* __restrict__ d0, int nb0,
          const float* __restrict__ s1, unsigned short* __restrict__ d1, int nb1,
          const float* __restrict__ s2, unsigned short* __restrict__ d2)
{
  const int b = blockIdx.x;
  const float* s; unsigned short* d; int base;
  if (b < nb0)            { s = s0; d = d0; base = b << 11; }
  else if (b < nb0 + nb1) { s = s1; d = d1; base = (b - nb0) << 11; }
  else                    { s = s2; d = d2; base = (b - nb0 - nb1) << 11; }
  const int i = base + (int)threadIdx.x * 8;
  const float4 a0 = *(const float4*)(s + i);
  const float4 a1 = *(const float4*)(s + i + 4);
  u16x8 v;
  v[0]=f2bf(a0.x); v[1]=f2bf(a0.y); v[2]=f2bf(a0.z); v[3]=f2bf(a0.w);
  v[4]=f2bf(a1.x); v[5]=f2bf(a1.y); v[6]=f2bf(a1.z); v[7]=f2bf(a1.w);
  *(u16x8*)(d + i) = v;
}

// out = p[0] + p[1] + bias  (split-K reduce, fp32, float4)
__global__ __launch_bounds__(256)
void reduce2(const float* __restrict__ p, const float* __restrict__ bias,
             float* __restrict__ out)
{
  const size_t i = ((size_t)blockIdx.x * 256 + threadIdx.x) * 4;
  const int col = (int)(i & (HIDN - 1));
  const float4 a = *(const float4*)(p + i);
  const float4 b = *(const float4*)(p + (size_t)TTOK * HIDN + i);
  const float4 c = *(const float4*)(bias + col);
  float4 r;
  r.x = a.x + b.x + c.x; r.y = a.y + b.y + c.y;
  r.z = a.z + b.z + c.z; r.w = a.w + b.w + c.w;
  *(float4*)(out + i) = r;
}

// C[M,N] = A[M,K] * B[N,K]^T (+ bias), bf16 in.  8 waves (2M x 4N) interleaved.
// BK=64, 2 K-tile LDS dbuf in row-halves.  Phases (A0B0)(A0B1)(A1B1)(A1B0);
// B0 frags held in registers across the K-tile so q3 does no LDS reads and its
// MFMA runs before its vmcnt wait.  Steady waits vmcnt(4); vmcnt(0) only
// prologue + last tile.  Barriers only after waits (3/K-tile).  LDS XOR-swizzle.
// MODE 0: GEMM1 — Q cols -> Cp row-major bf16 PRE-SCALED by QKSCALE,
//         K/V cols -> ctt tiled.
// MODE 1: split-K partial — fp32, no bias, to Cp + z*M*N; kOff = z*K.
template<int MW, int MODE>
__global__ __launch_bounds__(512, 2)
void gemm_8ph(const unsigned short* __restrict__ A, const unsigned short* __restrict__ B,
              const float* __restrict__ bias, void* __restrict__ Cp,
              unsigned short* __restrict__ ctt, int K, int lda, int ldb, int ldc)
{
  constexpr int BM   = MW * 32;          // 256
  constexpr int MH   = MW / 2;           // 4
  constexpr int ALD2 = MW / 4;           // 2
  __shared__ __align__(16) unsigned short As[2][2][(BM / 2) * 64];
  __shared__ __align__(16) unsigned short Bs[2][2][128 * 64];

  const int tid  = threadIdx.x;
  const int lane = tid & 63, wid = tid >> 6;
  const int wm = wid >> 2, wn = wid & 3;            // 2 x 4 wave grid
  const int m0 = blockIdx.y * BM, n0 = blockIdx.x * 256;
  const int l15 = lane & 15, lg = lane >> 4;
  const int kOff = (MODE == 1) ? blockIdx.z * K : 0;

  // staging: linear LDS dest, inverse-swizzled global source
  const int srow = tid >> 3;                                  // 0..63
  const int scol = ((tid & 7) ^ ((tid >> 3) & 7)) << 3;
  // fragment reads: swizzled col constants (row&7 == l15&7 for all frags)
  const int rsw = (l15 & 7) << 3;
  const int ck0 = (lg * 8) ^ rsw;
  const int ck1 = (32 + lg * 8) ^ rsw;
  const int arh = wm * 16 + l15;        // + mi_local*32 within half
  const int brh = wn * 16 + l15;        // + ni_local*64 within half

  auto stageAh = [&](int kt, int buf, int h) {
    #pragma unroll
    for (int i = 0; i < ALD2; ++i)
      g2l16(A + (size_t)(m0 + h * (BM / 2) + i * 64 + srow) * lda + kOff + kt + scol,
            &As[buf][h][(i * 512 + tid) * 8]);
  };
  auto stageBh = [&](int kt, int buf, int h) {
    #pragma unroll
    for (int i = 0; i < 2; ++i)
      g2l16(B + (size_t)(n0 + h * 128 + i * 64 + srow) * ldb + kOff + kt + scol,
            &Bs[buf][h][(i * 512 + tid) * 8]);
  };

  fx4 acc[MW][4] = {};

  const int nk = K >> 6;
  stageAh(0, 0, 0); stageBh(0, 0, 0); stageBh(0, 0, 1); stageAh(0, 0, 1);
  asm volatile("s_waitcnt vmcnt(0)" ::: "memory");
  __builtin_amdgcn_s_barrier();

  for (int t = 0; t < nk; ++t) {
    const int buf = t & 1, nb = buf ^ 1;
    const int kt1 = (t + 1) << 6;
    const bool pre = (t + 1) < nk;
    const unsigned short* A0 = &As[buf][0][0];
    const unsigned short* A1 = &As[buf][1][0];
    const unsigned short* B0 = &Bs[buf][0][0];
    const unsigned short* B1 = &Bs[buf][1][0];
    s16x8 af[MH][2], bf0[2][2], bf1[2][2];

    // ---------- q0: (A0,B0) -> acc[m][0..1]; stage Ah0'; wait drains Bh1(t) ----------
    #pragma unroll
    for (int m = 0; m < MH; ++m) {
      af[m][0] = *(const s16x8*)&A0[(arh + m * 32) * 64 + ck0];
      af[m][1] = *(const s16x8*)&A0[(arh + m * 32) * 64 + ck1];
    }
    #pragma unroll
    for (int n = 0; n < 2; ++n) {
      bf0[n][0] = *(const s16x8*)&B0[(brh + n * 64) * 64 + ck0];
      bf0[n][1] = *(const s16x8*)&B0[(brh + n * 64) * 64 + ck1];
    }
    if (pre) {
      stageAh(kt1, nb, 0);
      asm volatile("s_waitcnt vmcnt(4)" ::: "memory");
    } else {
      asm volatile("s_waitcnt vmcnt(0)" ::: "memory");
    }
    __builtin_amdgcn_s_barrier();
    __builtin_amdgcn_s_setprio(1);
    #pragma unroll
    for (int m = 0; m < MH; ++m)
      #pragma unroll
      for (int n = 0; n < 2; ++n) {
        acc[m][n] = __builtin_amdgcn_mfma_f32_16x16x32_bf16(af[m][0], bf0[n][0], acc[m][n], 0, 0, 0);
        acc[m][n] = __builtin_amdgcn_mfma_f32_16x16x32_bf16(af[m][1], bf0[n][1], acc[m][n], 0, 0, 0);
      }
    __builtin_amdgcn_s_setprio(0);

    // ---------- q1: (A0,B1) -> acc[m][2..3]; stage Bh0'; wait drains Ah1(t) ----------
    #pragma unroll
    for (int n = 0; n < 2; ++n) {
      bf1[n][0] = *(const s16x8*)&B1[(brh + n * 64) * 64 + ck0];
      bf1[n][1] = *(const s16x8*)&B1[(brh + n * 64) * 64 + ck1];
    }
    if (pre) {
      stageBh(kt1, nb, 0);
      asm volatile("s_waitcnt vmcnt(4)" ::: "memory");
    }
    __builtin_amdgcn_s_barrier();
    __builtin_amdgcn_s_setprio(1);
    #pragma unroll
    for (int m = 0; m < MH; ++m)
      #pragma unroll
      for (int n = 0; n < 2; ++n) {
        acc[m][2 + n] = __builtin_amdgcn_mfma_f32_16x16x32_bf16(af[m][0], bf1[n][0], acc[m][2 + n], 0, 0, 0);
        acc[m][2 + n] = __builtin_amdgcn_mfma_f32_16x16x32_bf16(af[m][1], bf1[n][1], acc[m][2 + n], 0, 0, 0);
      }
    __builtin_amdgcn_s_setprio(0);

    // ---------- q2: (A1,B1) -> acc[MH+m][2..3]; stage Bh1'; no wait, no barrier ----------
    #pragma unroll
    for (int m = 0; m < MH; ++m) {
      af[m][0] = *(const s16x8*)&A1[(arh + m * 32) * 64 + ck0];
      af[m][1] = *(const s16x8*)&A1[(arh + m * 32) * 64 + ck1];
    }
    if (pre) stageBh(kt1, nb, 1);
    __builtin_amdgcn_s_setprio(1);
    #pragma unroll
    for (int m = 0; m < MH; ++m)
      #pragma unroll
      for (int n = 0; n < 2; ++n) {
        acc[MH + m][2 + n] = __builtin_amdgcn_mfma_f32_16x16x32_bf16(af[m][0], bf1[n][0], acc[MH + m][2 + n], 0, 0, 0);
        acc[MH + m][2 + n] = __builtin_amdgcn_mfma_f32_16x16x32_bf16(af[m][1], bf1[n][1], acc[MH + m][2 + n], 0, 0, 0);
      }
    __builtin_amdgcn_s_setprio(0);

    // ---------- q3: (A1,B0) from REGISTERS -> acc[MH+m][0..1]; stage Ah1';
    //             MFMA first (no LDS dep), then wait (drains Ah0'+Bh0') ----------
    if (pre) stageAh(kt1, nb, 1);
    __builtin_amdgcn_s_setprio(1);
    #pragma unroll
    for (int m = 0; m < MH; ++m)
      #pragma unroll
      for (int n = 0; n < 2; ++n) {
        acc[MH + m][n] = __builtin_amdgcn_mfma_f32_16x16x32_bf16(af[m][0], bf0[n][0], acc[MH + m][n], 0, 0, 0);
        acc[MH + m][n] = __builtin_amdgcn_mfma_f32_16x16x32_bf16(af[m][1], bf0[n][1], acc[MH + m][n], 0, 0, 0);
      }
    __builtin_amdgcn_s_setprio(0);
    if (pre) asm volatile("s_waitcnt vmcnt(4)" ::: "memory");
    __builtin_amdgcn_s_barrier();
  }

  // epilogue: row = m0 + mi*32 + wm*16 + lg*4+jj ; col = n0 + ni*64 + wn*16 + l15
  const int rb = m0 + wm * 16;
  const int cb = n0 + wn * 16;
  if (MODE == 1) {
    float* P = (float*)Cp + (size_t)blockIdx.z * (size_t)gridDim.y * BM * ldc;
    #pragma unroll
    for (int mi = 0; mi < MW; ++mi)
      #pragma unroll
      for (int ni = 0; ni < 4; ++ni) {
        const int col = cb + ni * 64 + l15;
        const fx4 a = acc[mi][ni];
        #pragma unroll
        for (int jj = 0; jj < 4; ++jj)
          P[(size_t)(rb + mi * 32 + lg * 4 + jj) * ldc + col] = a[jj];
      }
  } else if (n0 >= VOFF) {
    #pragma unroll
    for (int mi = 0; mi < MW; ++mi)
      #pragma unroll
      for (int ni = 0; ni < 4; ++ni) {
        const int col = cb + ni * 64 + l15;
        const float bv = bias[col];
        const fx4 a = acc[mi][ni];
        ushort4 pk;
        pk.x = f2bf(a[0] + bv); pk.y = f2bf(a[1] + bv);
        pk.z = f2bf(a[2] + bv); pk.w = f2bf(a[3] + bv);
        const int d   = col - VOFF;
        const int kvp = d >> 8, dw = d & 255;
        const int row0 = rb + mi * 32 + lg * 4;      // key
        const int kt2 = row0 >> 5, kk = row0 & 31;
        const int kc = kk >> 3, k8 = kk & 7;
        *(ushort4*)&ctt[(size_t)kvp * 1048576 + (size_t)kt2 * 16384 + 8192
                        + kc * 2048 + dw * 8 + k8] = pk;
      }
  } else if (n0 >= KOFF) {
    #pragma unroll
    for (int mi = 0; mi < MW; ++mi)
      #pragma unroll
      for (int ni = 0; ni < 4; ++ni) {
        const int col = cb + ni * 64 + l15;
        const int ccol = col - KOFF;
        const float bv = bias[col];
        const int kvp = ccol >> 8, cw = ccol & 255;
        const int cc = cw >> 3, cbt = cw & 7;
        const fx4 a = acc[mi][ni];
        #pragma unroll
        for (int jj = 0; jj < 4; ++jj) {
          const int row2 = rb + mi * 32 + lg * 4 + jj;   // key
          const int kt2 = row2 >> 5, kk = row2 & 31;
          ctt[(size_t)kvp * 1048576 + (size_t)kt2 * 16384 + cc * 256 + kk * 8 + cbt]
              = f2bf(a[jj] + bv);
        }
      }
  } else {
    // Q region: pre-scale by QKSCALE (folded out of the attention kernel)
    #pragma unroll
    for (int mi = 0; mi < MW; ++mi)
      #pragma unroll
      for (int ni = 0; ni < 4; ++ni) {
        const int col = cb + ni * 64 + l15;
        const float bv = bias[col];
        const fx4 a = acc[mi][ni];
        #pragma unroll
        for (int jj = 0; jj < 4; ++jj) {
          const int row2 = rb + mi * 32 + lg * 4 + jj;
          ((unsigned short*)Cp)[(size_t)row2 * ldc + col] = f2bf((a[jj] + bv) * QKSCALE);
        }
      }
  }
}

// Block = (pair, 64 q-rows), 4 waves (16 rows each, both diff components).
// COMPLEMENTARY BALANCED decode: bids b (heavy, qb=31-x) and b+256 (light,
// qb=x) share r=bid&255 -> same pair (KV L2 reuse) and tile counts summing
// to a constant 66 on every CU (round-robin-mod-8-XCD dispatch model).
// K/V staged per 32-key tile via global_load_lds from the tile-contiguous ctt,
// double-buffered, ONE barrier per tile. Q arrives pre-scaled by QKSCALE.
__global__ __launch_bounds__(256, 2)
void attn_kernel(const unsigned short* __restrict__ qq,    // [TTOK][HIDN] bf16 Q*scale
                 const unsigned short* __restrict__ ctt,   // tiled K/V
                 const float* __restrict__ lq1, const float* __restrict__ lk1,
                 const float* __restrict__ lq2, const float* __restrict__ lk2,
                 const float* __restrict__ subln,
                 unsigned short* __restrict__ attn_out)    // [TTOK][HIDN] bf16
{
  __shared__ __align__(16) unsigned short Sb[2][16384];    // [K 16KB][V 16KB]
  __shared__ __align__(16) unsigned short Pl[4][2][640];
  const int tid = threadIdx.x;
  const int lane = tid & 63, w = tid >> 6;
  const int l15 = lane & 15, lg = lane >> 4;

  // balanced decode
  const int bid  = blockIdx.x;
  const int r    = bid & 255;
  const int pair = r & 15;
  const int x    = r >> 4;                    // 0..15
  const int qb   = (bid >> 8) ? x : 31 - x;   // heavy half first
  const int kvp  = pair >> 2;
  const int q0b  = qb * 64;
  const int q0w  = q0b + w * 16;
  const int nt   = 2 * qb + 2;

  const unsigned short* cbase = ctt + (size_t)kvp * 1048576;

  // stage tile kt (32KB linear) into Sb[buf]: 8 x global_load_lds(16B) per wave
  auto stage = [&](int kt, int buf) {
    const unsigned short* src = cbase + (size_t)kt * 16384;
    const int off = w * 512 + lane * 8;
    #pragma unroll
    for (int i = 0; i < 8; ++i) {
      const int o = i * 2048 + off;
      g2l16(src + o, &Sb[buf][o]);
    }
  };

  stage(0, 0);

  // lambda via wave-parallel dot
  float a1 = lq1[lane] * lk1[lane] + lq1[lane + 64] * lk1[lane + 64];
  float a2 = lq2[lane] * lk2[lane] + lq2[lane + 64] * lk2[lane + 64];
  #pragma unroll
  for (int sft = 1; sft < 64; sft <<= 1) { a1 += __shfl_xor(a1, sft); a2 += __shfl_xor(a2, sft); }
  const float lam = __expf(a1) - __expf(a2) + LAM_INIT;

  // Q fragments (pre-scaled)
  s16x8 qf0[4], qf1[4];
  {
    const unsigned short* qbp = qq + (size_t)(q0w + l15) * HIDN + pair * VD + lg * 8;
    #pragma unroll
    for (int kf = 0; kf < 4; ++kf) {
      qf0[kf] = *(const s16x8*)(qbp + kf * 32);
      qf1[kf] = *(const s16x8*)(qbp + DH + kf * 32);
    }
  }

  float mrun0 = -1e30f, mrun1 = -1e30f;
  float lrun0 = 0.f, lrun1 = 0.f;
  fx4 oacc0[16] = {}, oacc1[16] = {};
  unsigned short* pl0 = &Pl[w][0][0];
  unsigned short* pl1 = &Pl[w][1][0];
  const int q = q0w + l15;
  const int qmax = q0w + 15;

  for (int t = 0; t < nt; ++t) {
    __syncthreads();                      // stage(t) visible; buf[(t+1)&1] free
    if (t + 1 < nt) stage(t + 1, (t + 1) & 1);
    const int kb = t * 32;
    if (kb > qmax) continue;              // wave-uniform; still hits barrier next iter
    const unsigned short* Kl = Sb[t & 1];
    const unsigned short* Vl = Sb[t & 1] + 8192;

    // ---- QK^T swapped: S^T[key][q]
    fx4 s00 = {0,0,0,0}, s01 = {0,0,0,0}, s10 = {0,0,0,0}, s11 = {0,0,0,0};
    #pragma unroll
    for (int kf = 0; kf < 4; ++kf) {
      const int cc0 = kf * 4 + lg;        // comp0 chunks
      const int cc1 = 16 + kf * 4 + lg;   // comp1 chunks
      const s16x8 k00 = *(const s16x8*)&Kl[cc0 * 256 + l15 * 8];
      const s16x8 k01 = *(const s16x8*)&Kl[cc0 * 256 + (16 + l15) * 8];
      const s16x8 k10 = *(const s16x8*)&Kl[cc1 * 256 + l15 * 8];
      const s16x8 k11 = *(const s16x8*)&Kl[cc1 * 256 + (16 + l15) * 8];
      s00 = __builtin_amdgcn_mfma_f32_16x16x32_bf16(k00, qf0[kf], s00, 0, 0, 0);
      s01 = __builtin_amdgcn_mfma_f32_16x16x32_bf16(k01, qf0[kf], s01, 0, 0, 0);
      s10 = __builtin_amdgcn_mfma_f32_16x16x32_bf16(k10, qf1[kf], s10, 0, 0, 0);
      s11 = __builtin_amdgcn_mfma_f32_16x16x32_bf16(k11, qf1[kf], s11, 0, 0, 0);
    }

    // ---- mask (full-tile fast path: all 32 keys <= all 16 q rows)
    float v0[8], v1[8];
    if (kb + 32 <= q0w) {
      #pragma unroll
      for (int j = 0; j < 4; ++j) {
        v0[j] = s00[j]; v0[4 + j] = s01[j];
        v1[j] = s10[j]; v1[4 + j] = s11[j];
      }
    } else {
      #pragma unroll
      for (int j = 0; j < 4; ++j) {
        const int klo = kb + lg * 4 + j, khi = klo + 16;
        v0[j]     = (klo <= q) ? s00[j] : -1e30f;
        v0[4 + j] = (khi <= q) ? s01[j] : -1e30f;
        v1[j]     = (klo <= q) ? s10[j] : -1e30f;
        v1[4 + j] = (khi <= q) ? s11[j] : -1e30f;
      }
    }
    // ---- tile max per comp
    float tm0 = fmaxf(fmaxf(fmaxf(v0[0],v0[1]),fmaxf(v0[2],v0[3])),
                      fmaxf(fmaxf(v0[4],v0[5]),fmaxf(v0[6],v0[7])));
    float tm1 = fmaxf(fmaxf(fmaxf(v1[0],v1[1]),fmaxf(v1[2],v1[3])),
                      fmaxf(fmaxf(v1[4],v1[5]),fmaxf(v1[6],v1[7])));
    tm0 = fmaxf(tm0, __shfl_xor(tm0, 16)); tm0 = fmaxf(tm0, __shfl_xor(tm0, 32));
    tm1 = fmaxf(tm1, __shfl_xor(tm1, 16)); tm1 = fmaxf(tm1, __shfl_xor(tm1, 32));

    // ---- defer-max rescale (rare)
    const bool need = (tm0 > mrun0 + RESCALE_THR) || (tm1 > mrun1 + RESCALE_THR);
    if (__any(need)) {
      const float mn0 = fmaxf(mrun0, tm0), mn1 = fmaxf(mrun1, tm1);
      const float fac0 = __expf(mrun0 - mn0), fac1 = __expf(mrun1 - mn1);
      mrun0 = mn0; mrun1 = mn1;
      lrun0 *= fac0; lrun1 *= fac1;
      #pragma unroll
      for (int jj = 0; jj < 4; ++jj) {
        const float fr0 = __shfl(fac0, lg * 4 + jj);
        const float fr1 = __shfl(fac1, lg * 4 + jj);
        #pragma unroll
        for (int nf = 0; nf < 16; ++nf) { oacc0[nf][jj] *= fr0; oacc1[nf][jj] *= fr1; }
      }
    }

    // ---- P = exp(v - mrun), pack bf16 -> per-wave LDS transpose
    {
      float ps0 = 0.f, ps1 = 0.f;
      ushort4 lo0, hi0, lo1, hi1;
      float p;
      p = __expf(v0[0]-mrun0); ps0 += p; lo0.x = f2bf(p);
      p = __expf(v0[1]-mrun0); ps0 += p; lo0.y = f2bf(p);
      p = __expf(v0[2]-mrun0); ps0 += p; lo0.z = f2bf(p);
      p = __expf(v0[3]-mrun0); ps0 += p; lo0.w = f2bf(p);
      p = __expf(v0[4]-mrun0); ps0 += p; hi0.x = f2bf(p);
      p = __expf(v0[5]-mrun0); ps0 += p; hi0.y = f2bf(p);
      p = __expf(v0[6]-mrun0); ps0 += p; hi0.z = f2bf(p);
      p = __expf(v0[7]-mrun0); ps0 += p; hi0.w = f2bf(p);
      p = __expf(v1[0]-mrun1); ps1 += p; lo1.x = f2bf(p);
      p = __expf(v1[1]-mrun1); ps1 += p; lo1.y = f2bf(p);
      p = __expf(v1[2]-mrun1); ps1 += p; lo1.z = f2bf(p);
      p = __expf(v1[3]-mrun1); ps1 += p; lo1.w = f2bf(p);
      p = __expf(v1[4]-mrun1); ps1 += p; hi1.x = f2bf(p);
      p = __expf(v1[5]-mrun1); ps1 += p; hi1.y = f2bf(p);
      p = __expf(v1[6]-mrun1); ps1 += p; hi1.z = f2bf(p);
      p = __expf(v1[7]-mrun1); ps1 += p; hi1.w = f2bf(p);
      lrun0 += ps0; lrun1 += ps1;
      *(ushort4*)&pl0[l15 * 40 + lg * 4]      = lo0;
      *(ushort4*)&pl0[l15 * 40 + 16 + lg * 4] = hi0;
      *(ushort4*)&pl1[l15 * 40 + lg * 4]      = lo1;
      *(ushort4*)&pl1[l15 * 40 + 16 + lg * 4] = hi1;
    }
    asm volatile("s_waitcnt lgkmcnt(0)" ::: "memory");
    __builtin_amdgcn_sched_barrier(0);

    // ---- PV from LDS V tile (conflict-free layout)
    const s16x8 pa0 = *(const s16x8*)&pl0[l15 * 40 + lg * 8];
    const s16x8 pa1 = *(const s16x8*)&pl1[l15 * 40 + lg * 8];
    #pragma unroll
    for (int nf = 0; nf < 16; ++nf) {
      const s16x8 vf = *(const s16x8*)&Vl[lg * 2048 + (nf * 16 + l15) * 8];
      oacc0[nf] = __builtin_amdgcn_mfma_f32_16x16x32_bf16(pa0, vf, oacc0[nf], 0, 0, 0);
      oacc1[nf] = __builtin_amdgcn_mfma_f32_16x16x32_bf16(pa1, vf, oacc1[nf], 0, 0, 0);
    }
  }

  // ---- finalize row sums
  lrun0 += __shfl_xor(lrun0, 16); lrun0 += __shfl_xor(lrun0, 32);
  lrun1 += __shfl_xor(lrun1, 16); lrun1 += __shfl_xor(lrun1, 32);

  float li0[4], li1[4];
  #pragma unroll
  for (int jj = 0; jj < 4; ++jj) {
    li0[jj] = 1.0f / __shfl(lrun0, lg * 4 + jj);
    li1[jj] = 1.0f / __shfl(lrun1, lg * 4 + jj);
  }

  // ---- combine, RMSNorm over 256, scale, store
  float ss[4] = {0.f, 0.f, 0.f, 0.f};
  #pragma unroll
  for (int nf = 0; nf < 16; ++nf)
    #pragma unroll
    for (int jj = 0; jj < 4; ++jj) {
      const float o = oacc0[nf][jj] * li0[jj] - lam * oacc1[nf][jj] * li1[jj];
      oacc0[nf][jj] = o;
      ss[jj] += o * o;
    }
  #pragma unroll
  for (int jj = 0; jj < 4; ++jj) {
    ss[jj] += __shfl_xor(ss[jj], 1);
    ss[jj] += __shfl_xor(ss[jj], 2);
    ss[jj] += __shfl_xor(ss[jj], 4);
    ss[jj] += __shfl_xor(ss[jj], 8);
    ss[jj] = rsqrtf(ss[jj] * (1.0f / 256.0f) + 1e-5f) * OML;
  }
  #pragma unroll
  for (int nf = 0; nf < 16; ++nf) {
    const int dcol = nf * 16 + l15;
    const float sw = subln[dcol];
    #pragma unroll
    for (int jj = 0; jj < 4; ++jj) {
      const int t = q0w + lg * 4 + jj;
      attn_out[(size_t)t * HIDN + pair * VD + dcol] = f2bf(oacc0[nf][jj] * ss[jj] * sw);
    }
  }
}

extern "C" void kernel_launch(void* const* d_in, const int* in_sizes, int n_in,
                              void* d_out, int out_size, void* d_ws, size_t ws_size,
                              hipStream_t stream) {
  (void)in_sizes; (void)n_in; (void)out_size; (void)ws_size;
  const float* hs     = (const float*)d_in[0];
  const float* wqkv_w = (const float*)d_in[1];
  const float* wqkv_b = (const float*)d_in[2];
  const float* lq1    = (const float*)d_in[3];
  const float* lk1    = (const float*)d_in[4];
  const float* lq2    = (const float*)d_in[5];
  const float* lk2    = (const float*)d_in[6];
  const float* subln  = (const float*)d_in[7];
  const float* out_w  = (const float*)d_in[8];
  const float* out_b  = (const float*)d_in[9];

  // ws layout (all bf16/ushort):
  //   qq [2048][4096] | ctt 4x1048576 | attn_out [2048][4096]
  //   hs_bf [2048*4096] | wqkv_bf [6144*4096] | outw_bf [4096*4096]   (~140 MB)
  // hs_bf+wqkv_bf (66 MB, dead after GEMM1) are overlaid by the 64 MB split-K
  // partial buffer during GEMM2.
  unsigned short* qq       = (unsigned short*)d_ws;
  unsigned short* ctt      = qq + (size_t)TTOK * HIDN;
  unsigned short* attn_out = ctt + (size_t)4 * 1048576;
  unsigned short* hs_bf    = attn_out + (size_t)TTOK * HIDN;
  unsigned short* wqkv_bf  = hs_bf + (size_t)TTOK * HIDN;
  unsigned short* outw_bf  = wqkv_bf + (size_t)OPD * HIDN;
  float*          partial  = (float*)hs_bf;   // 2 x [2048][4096] fp32

  const int nb0 = (TTOK * HIDN) >> 11;          // 4096
  const int nb1 = (OPD * HIDN) >> 11;           // 12288
  const int nb2 = (HIDN * HIDN) >> 11;          // 8192
  cvt3<<<dim3(nb0 + nb1 + nb2), 256, 0, stream>>>(
      hs, hs_bf, nb0, wqkv_w, wqkv_bf, nb1, out_w, outw_bf);

  // GEMM1: 256x256 tile; Q -> qq row-major (pre-scaled); K/V -> ctt tiled
  gemm_8ph<8, 0><<<dim3(OPD / 256, TTOK / 256), 512, 0, stream>>>(
      hs_bf, wqkv_bf, wqkv_b, qq, ctt, HIDN, HIDN, HIDN, HIDN);

  // Attention + combine + RMSNorm -> attn_out (bf16)
  attn_kernel<<<dim3(512), 256, 0, stream>>>(
      qq, ctt, lq1, lk1, lq2, lk2, subln, attn_out);

  // GEMM2 split-K: 256 blocks (16 x 8 x 2), each K=2048 -> fp32 partials
  gemm_8ph<8, 1><<<dim3(HIDN / 256, TTOK / 256, 2), 512, 0, stream>>>(
      attn_out, outw_bf, nullptr, partial, nullptr, HIDN / 2, HIDN, HIDN, HIDN);

  // out = partial0 + partial1 + out_b
  reduce2<<<dim3((TTOK * HIDN) / 1024), 256, 0, stream>>>(
      partial, out_b, (float*)d_out);
}